// Round 10
// baseline (289.903 us; speedup 1.0000x reference)
//
#include <hip/hip_runtime.h>
#include <hip/hip_bf16.h>
#include <math.h>

typedef __bf16 bf16_t;
typedef __bf16 bf16x8 __attribute__((ext_vector_type(8)));
typedef float f32x4 __attribute__((ext_vector_type(4)));

constexpr int Bc = 2, Tc = 2048, Cdim = 2048, Hc = 16, KVc = 4, HDc = 128;
constexpr int Mc = Bc * Tc;      // 4096
constexpr int Nqkv = 3072;       // fused projection width: 2048 Q + 512 K + 512 V

typedef const __attribute__((address_space(1))) void* as1_cptr;
typedef __attribute__((address_space(3))) void* as3_ptr;

__device__ __forceinline__ void gload_lds16(const bf16_t* g, bf16_t* l) {
  __builtin_amdgcn_global_load_lds((as1_cptr)(const void*)g, (as3_ptr)(void*)l, 16, 0, 0);
}

__device__ __forceinline__ unsigned int cvt_pk_bf16(float lo, float hi) {
  unsigned int r;
  asm("v_cvt_pk_bf16_f32 %0, %1, %2" : "=v"(r) : "v"(lo), "v"(hi));
  return r;
}
__device__ __forceinline__ void perm32swap(unsigned int& a, unsigned int& b) {
  asm("v_permlane32_swap_b32 %0, %1" : "+v"(a), "+v"(b));
}
__device__ __forceinline__ void perm16swap(unsigned int& a, unsigned int& b) {
  asm("v_permlane16_swap_b32 %0, %1" : "+v"(a), "+v"(b));
}
// guaranteed single-instruction exp2 (inputs bounded, no denormal concerns)
__device__ __forceinline__ float fast_exp2(float x) {
  float r;
  asm("v_exp_f32 %0, %1" : "=v"(r) : "v"(x));
  return r;
}

// ---------------- prep: x f32->bf16 + 4 weight transpose-converts, 1 launch
// tile padded [64][73] (odd half-stride kills the 16-way transpose conflict)
__global__ void k_prep(const float* __restrict__ x, bf16_t* __restrict__ xb,
                       const float* __restrict__ Wq, const float* __restrict__ Wk,
                       const float* __restrict__ Wv, const float* __restrict__ Wo,
                       bf16_t* __restrict__ Wqt, bf16_t* __restrict__ Wkt,
                       bf16_t* __restrict__ Wvt, bf16_t* __restrict__ Wot) {
  __shared__ bf16_t tile[64][73];
  int bid = blockIdx.x;
  if (bid < 4096) {
    int i = (bid * 256 + threadIdx.x) * 8;
    float4 a = *(const float4*)(x + i);
    float4 b = *(const float4*)(x + i + 4);
    bf16x8 v;
    v[0] = (bf16_t)a.x; v[1] = (bf16_t)a.y; v[2] = (bf16_t)a.z; v[3] = (bf16_t)a.w;
    v[4] = (bf16_t)b.x; v[5] = (bf16_t)b.y; v[6] = (bf16_t)b.z; v[7] = (bf16_t)b.w;
    *(bf16x8*)(xb + i) = v;
    return;
  }
  bid -= 4096;
  const float* W; bf16_t* Wt; int K, N, k0, n0;
  if (bid < 1024)      { W = Wq; Wt = Wqt; K = 2048; N = 2048; k0 = (bid >> 5) * 64; n0 = (bid & 31) * 64; }
  else if (bid < 1280) { bid -= 1024; W = Wk; Wt = Wkt; K = 2048; N = 512; k0 = (bid >> 3) * 64; n0 = (bid & 7) * 64; }
  else if (bid < 1536) { bid -= 1280; W = Wv; Wt = Wvt; K = 2048; N = 512; k0 = (bid >> 3) * 64; n0 = (bid & 7) * 64; }
  else                 { bid -= 1536; W = Wo; Wt = Wot; K = 2048; N = 2048; k0 = (bid >> 5) * 64; n0 = (bid & 31) * 64; }
  const int t = threadIdx.x;
#pragma unroll
  for (int i = 0; i < 4; ++i) {
    int idx = t + i * 256;
    int r = idx >> 4;
    int c4 = (idx & 15) * 4;
    float4 v = *(const float4*)(W + (size_t)(k0 + r) * N + n0 + c4);
    tile[r][c4 + 0] = (bf16_t)v.x; tile[r][c4 + 1] = (bf16_t)v.y;
    tile[r][c4 + 2] = (bf16_t)v.z; tile[r][c4 + 3] = (bf16_t)v.w;
  }
  __syncthreads();
#pragma unroll
  for (int i = 0; i < 4; ++i) {
    int idx = t + i * 256;
    int n = idx >> 4;
    int kc = (idx & 15) * 4;
    alignas(8) bf16_t o[4];
#pragma unroll
    for (int j = 0; j < 4; ++j) o[j] = tile[kc + j][n];
    *(uint2*)(Wt + (size_t)(n0 + n) * K + k0 + kc) = *(uint2*)o;
  }
}

// ---------------- GEMM: C[M,N] = A[M,K] * Bt[N,K]^T (fp32 out, O-proj) ----
__global__ __launch_bounds__(256, 2) void k_gemm_bt(
    const bf16_t* __restrict__ A, const bf16_t* __restrict__ Bt,
    float* __restrict__ Cout, int M, int N, int K) {
  __shared__ alignas(16) bf16_t Ash[128 * 64];
  __shared__ alignas(16) bf16_t Bsh[128 * 64];
  const int tid = threadIdx.x;
  const int wave = tid >> 6, lane = tid & 63;
  const int col = lane & 15, quad = lane >> 4;
  const int gx = gridDim.x;
  const int nwg = gx * gridDim.y;
  int wg = blockIdx.y * gx + blockIdx.x;
  if ((nwg & 7) == 0) wg = (wg & 7) * (nwg >> 3) + (wg >> 3);
  const int m0 = (wg / gx) * 128, n0 = (wg % gx) * 128;
  const int wr = wave >> 1, wc = wave & 1;

  f32x4 acc[4][4];
#pragma unroll
  for (int i = 0; i < 4; ++i)
#pragma unroll
    for (int j = 0; j < 4; ++j) acc[i][j] = f32x4{0.f, 0.f, 0.f, 0.f};

  const int lrow = lane >> 3;
  const int lkc8 = (lane & 7) ^ lrow;

  for (int k0 = 0; k0 < K; k0 += 64) {
    __syncthreads();
#pragma unroll
    for (int i = 0; i < 4; ++i) {
      const int rb = wave * 32 + i * 8;
      gload_lds16(A + (size_t)(m0 + rb + lrow) * K + k0 + lkc8 * 8, Ash + rb * 64);
      gload_lds16(Bt + (size_t)(n0 + rb + lrow) * K + k0 + lkc8 * 8, Bsh + rb * 64);
    }
    __syncthreads();
#pragma unroll
    for (int kc = 0; kc < 2; ++kc) {
      bf16x8 af[4], bfr[4];
#pragma unroll
      for (int mt = 0; mt < 4; ++mt) {
        const int m = wr * 64 + mt * 16 + col;
        const int slot = (kc * 4 + quad) ^ (m & 7);
        af[mt] = *(const bf16x8*)(Ash + m * 64 + slot * 8);
      }
#pragma unroll
      for (int nt = 0; nt < 4; ++nt) {
        const int n = wc * 64 + nt * 16 + col;
        const int slot = (kc * 4 + quad) ^ (n & 7);
        bfr[nt] = *(const bf16x8*)(Bsh + n * 64 + slot * 8);
      }
#pragma unroll
      for (int mt = 0; mt < 4; ++mt)
#pragma unroll
        for (int nt = 0; nt < 4; ++nt)
          acc[mt][nt] = __builtin_amdgcn_mfma_f32_16x16x32_bf16(
              af[mt], bfr[nt], acc[mt][nt], 0, 0, 0);
    }
  }
#pragma unroll
  for (int mt = 0; mt < 4; ++mt)
#pragma unroll
    for (int i = 0; i < 4; ++i) {
      const int row = m0 + wr * 64 + mt * 16 + quad * 4 + i;
#pragma unroll
      for (int nt = 0; nt < 4; ++nt)
        Cout[(size_t)row * N + n0 + wc * 64 + nt * 16 + col] = acc[mt][nt][i];
    }
}

// ---------------- fused QKV GEMM + RoPE + head-repack + V-transpose ------
__global__ __launch_bounds__(256, 3) void k_gemm_qkv(
    const bf16_t* __restrict__ A, const bf16_t* __restrict__ Bt,
    const float* __restrict__ cs, const float* __restrict__ sn,
    bf16_t* __restrict__ Qp, bf16_t* __restrict__ Kp, bf16_t* __restrict__ Vt) {
  constexpr int K = Cdim;
  __shared__ alignas(16) bf16_t Ash[128 * 64];
  __shared__ alignas(16) bf16_t Bsh[128 * 64];
  const int tid = threadIdx.x;
  const int wave = tid >> 6, lane = tid & 63;
  const int col = lane & 15, quad = lane >> 4;
  const int gx = gridDim.x;
  const int nwg = gx * gridDim.y;
  int wg = blockIdx.y * gx + blockIdx.x;
  wg = (wg & 7) * (nwg >> 3) + (wg >> 3);
  const int m0 = (wg / gx) * 128;
  const int bxi = wg % gx;
  const int n0 = bxi * 128;

  f32x4 acc[2][8];
#pragma unroll
  for (int i = 0; i < 2; ++i)
#pragma unroll
    for (int j = 0; j < 8; ++j) acc[i][j] = f32x4{0.f, 0.f, 0.f, 0.f};

  const int lrow = lane >> 3;
  const int lkc8 = (lane & 7) ^ lrow;

  for (int k0 = 0; k0 < K; k0 += 64) {
    __syncthreads();
#pragma unroll
    for (int i = 0; i < 4; ++i) {
      const int rb = wave * 32 + i * 8;
      gload_lds16(A + (size_t)(m0 + rb + lrow) * K + k0 + lkc8 * 8, Ash + rb * 64);
      gload_lds16(Bt + (size_t)(n0 + rb + lrow) * K + k0 + lkc8 * 8, Bsh + rb * 64);
    }
    __syncthreads();
#pragma unroll
    for (int kc = 0; kc < 2; ++kc) {
      bf16x8 af[2], bfr[8];
#pragma unroll
      for (int mt = 0; mt < 2; ++mt) {
        const int m = wave * 32 + mt * 16 + col;
        const int slot = (kc * 4 + quad) ^ (m & 7);
        af[mt] = *(const bf16x8*)(Ash + m * 64 + slot * 8);
      }
#pragma unroll
      for (int nt = 0; nt < 8; ++nt) {
        const int n = nt * 16 + col;
        const int slot = (kc * 4 + quad) ^ (n & 7);
        bfr[nt] = *(const bf16x8*)(Bsh + n * 64 + slot * 8);
      }
#pragma unroll
      for (int mt = 0; mt < 2; ++mt)
#pragma unroll
        for (int nt = 0; nt < 8; ++nt)
          acc[mt][nt] = __builtin_amdgcn_mfma_f32_16x16x32_bf16(
              af[mt], bfr[nt], acc[mt][nt], 0, 0, 0);
    }
  }

  const int bx = bxi;   // head-tile: 0-15 Q, 16-19 K, 20-23 V
  if (bx < 20) {
    const bool isQ = bx < 16;
#pragma unroll
    for (int mt = 0; mt < 2; ++mt)
#pragma unroll
      for (int i = 0; i < 4; ++i) {
        const int row = m0 + wave * 32 + mt * 16 + quad * 4 + i;
        const int b = row >> 11, t = row & (Tc - 1);
        bf16_t* op = isQ ? Qp + ((size_t)(b * Hc + bx) * Tc + t) * HDc
                         : Kp + ((size_t)(b * KVc + (bx - 16)) * Tc + t) * HDc;
        const float* cr = cs + t * HDc;
        const float* sr = sn + t * HDc;
#pragma unroll
        for (int nt = 0; nt < 4; ++nt) {
          const int d = nt * 16 + col;
          const float c = cr[d], s = sr[d];
          const float x0 = acc[mt][nt][i], x1 = acc[mt][nt + 4][i];
          op[d]      = (bf16_t)(x0 * c - x1 * s);
          op[d + 64] = (bf16_t)(x1 * c + x0 * s);
        }
      }
  } else {
    const int kv = bx - 20;
#pragma unroll
    for (int mt = 0; mt < 2; ++mt) {
      const int row0 = m0 + wave * 32 + mt * 16 + quad * 4;
      const int b = row0 >> 11, t0 = row0 & (Tc - 1);
#pragma unroll
      for (int nt = 0; nt < 8; ++nt) {
        const int d = nt * 16 + col;
        alignas(8) bf16_t o[4];
#pragma unroll
        for (int i = 0; i < 4; ++i) o[i] = (bf16_t)acc[mt][nt][i];
        *(uint2*)(Vt + ((size_t)(b * KVc + kv) * HDc + d) * Tc + t0) = *(uint2*)o;
      }
    }
  }
}

// ---------------- Flash attention v12: cross-iteration PV pipeline (T15) --
// Region r: {barrier; stage K(r+1)+V(r); vmcnt(8); barrier; QK(r) + PV(r-1)
// as one dense 32-MFMA cluster; exp/pack(r) -> saved P}. P(r)'s VALU results
// aren't consumed until region r+1, so the serial QK->exp->PV chain is gone.
// V staged exactly 1 region before consumption (K unchanged); vmcnt(8) waits
// precisely the previous region's 8 loads. P single-buffered (written after
// PV consumed it). Both passes' Q fragments preloaded. Pass merge through
// the dead V buffer in two 32KB halves.
__global__ __launch_bounds__(512, 2) void k_attn(
    const bf16_t* __restrict__ Qp, const bf16_t* __restrict__ Kp,
    const bf16_t* __restrict__ Vt, bf16_t* __restrict__ Oout) {
  constexpr float sc2 = 0.08838834764831845f * 1.4426950408889634f; // scale*log2(e)
  __shared__ alignas(16) bf16_t Ksh[2][2][64 * 128];  // [buf][parity], swz ^(r&7)
  __shared__ alignas(16) bf16_t Vsh[2][2][128 * 64];  // [buf][parity], swz ^(d&7)
  __shared__ float lex[4][64][2];                     // l exchange

  const int wg = blockIdx.x;
  const int g = wg & 7, kslot = wg >> 3;
  const int kvh = g & 3, b = g >> 2;
  const int h = kvh * 4 + (kslot >> 3);
  const int i2 = kslot & 7;

  const int tid = threadIdx.x, wave = tid >> 6, lane = tid & 63;
  const int wq = wave & 3, wk = wave >> 2;
  const int col = lane & 15, quad = lane >> 4;

  const bf16_t* Kb = Kp + (size_t)(b * KVc + kvh) * Tc * HDc;
  const bf16_t* Vb = Vt + (size_t)(b * KVc + kvh) * HDc * Tc;
  const bf16_t* Qbh = Qp + (size_t)(b * Hc + h) * Tc * HDc;

  const int st_kr = lane >> 4, st_kc8 = lane & 15;
  const int st_vr = lane >> 3, st_vc8 = lane & 7;

  const int qt0 = 15 - i2, qt1 = i2;
  const int PT0 = qt0 + 1;     // tiles in pass 0; 17 tiles total (s=0..16)

  const int q0p0 = qt0 * 128 + wq * 32;
  const int q0p1 = qt1 * 128 + wq * 32;
  int q0 = q0p0;

  // preload BOTH passes' Q fragments (removes boundary reload latency)
  bf16x8 qA0[4], qB0[4], qA1[4], qB1[4];
  {
    const bf16_t* a0 = Qbh + (size_t)(q0p0 + col) * HDc;
    const bf16_t* b0 = Qbh + (size_t)(q0p0 + 16 + col) * HDc;
    const bf16_t* a1 = Qbh + (size_t)(q0p1 + col) * HDc;
    const bf16_t* b1 = Qbh + (size_t)(q0p1 + 16 + col) * HDc;
#pragma unroll
    for (int kc = 0; kc < 4; ++kc) {
      bf16x8 r0 = *(const bf16x8*)(a0 + kc * 32 + quad * 8);
      bf16x8 r1 = *(const bf16x8*)(b0 + kc * 32 + quad * 8);
      bf16x8 r2 = *(const bf16x8*)(a1 + kc * 32 + quad * 8);
      bf16x8 r3 = *(const bf16x8*)(b1 + kc * 32 + quad * 8);
#pragma unroll
      for (int e = 0; e < 8; ++e) {
        qA0[kc][e] = (bf16_t)((float)r0[e] * sc2);
        qB0[kc][e] = (bf16_t)((float)r1[e] * sc2);
        qA1[kc][e] = (bf16_t)((float)r2[e] * sc2);
        qB1[kc][e] = (bf16_t)((float)r3[e] * sc2);
      }
    }
  }

  f32x4 oA[8], oB[8];
#pragma unroll
  for (int nb = 0; nb < 8; ++nb) {
    oA[nb] = f32x4{0.f, 0.f, 0.f, 0.f};
    oB[nb] = f32x4{0.f, 0.f, 0.f, 0.f};
  }
  float lA = 0.f, lB = 0.f;
  unsigned int pwA[4][2], pwB[4][2];   // saved P of tile r (consumed r+1)

  auto kvb_of = [&](int t) { const int tn = (t < PT0) ? t : t - PT0; return tn * 128 + wk * 64; };

  auto stageK = [&](int t) {
    bf16_t* Kd = &Ksh[t & 1][wk][0];
    const int kb = kvb_of(t);
#pragma unroll
    for (int i = 0; i < 4; ++i) {
      const int rb = wq * 16 + i * 4;
      const int r = rb + st_kr;
      const int kc8 = st_kc8 ^ (r & 7);
      gload_lds16(Kb + (size_t)(kb + r) * HDc + kc8 * 8, Kd + rb * 128);
    }
  };
  auto stageV = [&](int t) {
    bf16_t* Vd = &Vsh[t & 1][wk][0];
    const int kb = kvb_of(t);
#pragma unroll
    for (int i = 0; i < 4; ++i) {
      const int db = wq * 32 + i * 8;
      const int d = db + st_vr;
      const int tc8 = st_vc8 ^ (d & 7);
      gload_lds16(Vb + (size_t)d * Tc + kb + tc8 * 8, Vd + db * 64);
    }
  };

  auto qkc = [&](const bf16x8 (&qa)[4], const bf16x8 (&qb)[4],
                 f32x4 (&sA)[4], f32x4 (&sB)[4], const bf16_t* Kc) {
#pragma unroll
    for (int kc = 0; kc < 4; ++kc)
#pragma unroll
      for (int tb = 0; tb < 4; ++tb) {
        const int rr = tb * 16 + col;
        const int slot = (kc * 4 + quad) ^ (rr & 7);
        bf16x8 kf = *(const bf16x8*)(Kc + rr * 128 + slot * 8);
        sA[tb] = __builtin_amdgcn_mfma_f32_16x16x32_bf16(kf, qa[kc], sA[tb], 0, 0, 0);
        sB[tb] = __builtin_amdgcn_mfma_f32_16x16x32_bf16(kf, qb[kc], sB[tb], 0, 0, 0);
      }
  };

  auto pvc = [&](const bf16_t* Vc) {
#pragma unroll
    for (int kc = 0; kc < 2; ++kc) {
      unsigned int a0 = pwA[2 * kc][0], c0 = pwA[2 * kc + 1][0];
      unsigned int a1 = pwA[2 * kc][1], c1 = pwA[2 * kc + 1][1];
      perm32swap(a0, c0); perm32swap(a1, c1);
      perm16swap(a0, c0); perm16swap(a1, c1);
      union { unsigned int w[4]; bf16x8 v; } uA;
      uA.w[0] = a0; uA.w[1] = a1; uA.w[2] = c0; uA.w[3] = c1;
      unsigned int d0 = pwB[2 * kc][0], e0 = pwB[2 * kc + 1][0];
      unsigned int d1 = pwB[2 * kc][1], e1 = pwB[2 * kc + 1][1];
      perm32swap(d0, e0); perm32swap(d1, e1);
      perm16swap(d0, e0); perm16swap(d1, e1);
      union { unsigned int w[4]; bf16x8 v; } uB;
      uB.w[0] = d0; uB.w[1] = d1; uB.w[2] = e0; uB.w[3] = e1;
      const bf16x8 pfA = uA.v, pfB = uB.v;
#pragma unroll
      for (int nb = 0; nb < 8; ++nb) {
        const int d = nb * 16 + col;
        const int vslot = (kc * 4 + quad) ^ (d & 7);
        bf16x8 vf = *(const bf16x8*)(Vc + d * 64 + vslot * 8);
        oA[nb] = __builtin_amdgcn_mfma_f32_16x16x32_bf16(pfA, vf, oA[nb], 0, 0, 0);
        oB[nb] = __builtin_amdgcn_mfma_f32_16x16x32_bf16(pfB, vf, oB[nb], 0, 0, 0);
      }
    }
  };

  auto expp = [&](const f32x4 (&sA)[4], const f32x4 (&sB)[4], int kb, bool diag) {
    const int qrA = q0 + col, qrB = q0 + 16 + col;
#pragma unroll
    for (int tb = 0; tb < 4; ++tb) {
      const int kvb = kb + tb * 16 + quad * 4;
      float a0 = fast_exp2(sA[tb][0]), a1 = fast_exp2(sA[tb][1]);
      float a2 = fast_exp2(sA[tb][2]), a3 = fast_exp2(sA[tb][3]);
      float b0 = fast_exp2(sB[tb][0]), b1 = fast_exp2(sB[tb][1]);
      float b2 = fast_exp2(sB[tb][2]), b3 = fast_exp2(sB[tb][3]);
      if (diag) {
        a0 = (kvb + 0 > qrA) ? 0.f : a0;
        a1 = (kvb + 1 > qrA) ? 0.f : a1;
        a2 = (kvb + 2 > qrA) ? 0.f : a2;
        a3 = (kvb + 3 > qrA) ? 0.f : a3;
        b0 = (kvb + 0 > qrB) ? 0.f : b0;
        b1 = (kvb + 1 > qrB) ? 0.f : b1;
        b2 = (kvb + 2 > qrB) ? 0.f : b2;
        b3 = (kvb + 3 > qrB) ? 0.f : b3;
      }
      lA += (a0 + a1) + (a2 + a3);
      lB += (b0 + b1) + (b2 + b3);
      pwA[tb][0] = cvt_pk_bf16(a0, a1);
      pwA[tb][1] = cvt_pk_bf16(a2, a3);
      pwB[tb][0] = cvt_pk_bf16(b0, b1);
      pwB[tb][1] = cvt_pk_bf16(b2, b3);
    }
  };

  // two-half parity merge through a dead 32KB V buffer + O write
  auto combine = [&](float* dead, int q0o) {
    float* xo = dead + wq * 2048;
    asm volatile("s_barrier" ::: "memory");
    if (wk) {
#pragma unroll
      for (int nb = 0; nb < 8; ++nb) *(f32x4*)(xo + nb * 256 + lane * 4) = oA[nb];
      lex[wq][lane][0] = lA;
      lex[wq][lane][1] = lB;
    }
    asm volatile("s_waitcnt lgkmcnt(0)" ::: "memory");
    asm volatile("s_barrier" ::: "memory");
    if (!wk) {
#pragma unroll
      for (int nb = 0; nb < 8; ++nb) oA[nb] += *(const f32x4*)(xo + nb * 256 + lane * 4);
    }
    asm volatile("s_barrier" ::: "memory");
    if (wk) {
#pragma unroll
      for (int nb = 0; nb < 8; ++nb) *(f32x4*)(xo + nb * 256 + lane * 4) = oB[nb];
    }
    asm volatile("s_waitcnt lgkmcnt(0)" ::: "memory");
    asm volatile("s_barrier" ::: "memory");
    if (!wk) {
#pragma unroll
      for (int nb = 0; nb < 8; ++nb) oB[nb] += *(const f32x4*)(xo + nb * 256 + lane * 4);
      const float fA = lA + lex[wq][lane][0];
      const float fB = lB + lex[wq][lane][1];
#pragma unroll
      for (int gg = 0; gg < 2; ++gg) {
        float rs = gg ? fB : fA;
        rs += __shfl_xor(rs, 16);
        rs += __shfl_xor(rs, 32);
        const float inv = 1.0f / rs;
        const f32x4* oa = gg ? oB : oA;
        const int qbase = q0o + gg * 16;
#pragma unroll
        for (int i = 0; i < 4; ++i) {
          const float iq = __shfl(inv, quad * 4 + i);
          const int qrow = qbase + quad * 4 + i;
          bf16_t* op = Oout + ((size_t)(b * Tc) + qrow) * (Hc * HDc) + h * HDc;
#pragma unroll
          for (int nb = 0; nb < 8; ++nb) op[nb * 16 + col] = (bf16_t)(oa[nb][i] * iq);
        }
      }
    }
  };

  // prologue: K(0) + V(0) in flight (8 loads -> uniform vmcnt(8) at r=0)
  stageK(0); stageV(0);

#pragma unroll 1
  for (int r = 0; r <= 16; ++r) {
    asm volatile("s_barrier" ::: "memory");
    stageK(r < 16 ? r + 1 : 16);   // K one region ahead (dup at r=16 benign)
    stageV(r);                     // V consumed next region (dup at r=0 benign)
    asm volatile("s_waitcnt vmcnt(8)" ::: "memory");
    asm volatile("s_barrier" ::: "memory");

    f32x4 stA[4], stB[4];
#pragma unroll
    for (int tb = 0; tb < 4; ++tb) {
      stA[tb] = f32x4{0.f, 0.f, 0.f, 0.f};
      stB[tb] = f32x4{0.f, 0.f, 0.f, 0.f};
    }
    const bf16_t* Kc = &Ksh[r & 1][wk][0];
    __builtin_amdgcn_s_setprio(1);
    if (r < PT0) qkc(qA0, qB0, stA, stB, Kc);
    else         qkc(qA1, qB1, stA, stB, Kc);
    if (r >= 1)  pvc(&Vsh[(r - 1) & 1][wk][0]);   // deferred PV of tile r-1
    __builtin_amdgcn_s_setprio(0);

    if (r == PT0) {   // pass-0 accumulators complete (PV(PT0-1) just done)
      combine((float*)&Vsh[(PT0 - 1) & 1][0][0], q0);
#pragma unroll
      for (int nb = 0; nb < 8; ++nb) {
        oA[nb] = f32x4{0.f, 0.f, 0.f, 0.f};
        oB[nb] = f32x4{0.f, 0.f, 0.f, 0.f};
      }
      lA = 0.f; lB = 0.f;
      q0 = q0p1;
    }

    const bool diag = (r == PT0 - 1) || (r == 16);
    expp(stA, stB, kvb_of(r), diag);   // P for tile r -> consumed region r+1
  }

  // epilogue region: PV(16) + pass-1 merge
  asm volatile("s_barrier" ::: "memory");
  asm volatile("s_waitcnt vmcnt(0)" ::: "memory");
  asm volatile("s_barrier" ::: "memory");
  __builtin_amdgcn_s_setprio(1);
  pvc(&Vsh[0][wk][0]);                 // V(16) is in buffer 0
  __builtin_amdgcn_s_setprio(0);
  combine((float*)&Vsh[1][0][0], q0);  // buffer 1 (V(15)) is dead
}

// ---------------- launch ----------------
extern "C" void kernel_launch(void* const* d_in, const int* in_sizes, int n_in,
                              void* d_out, int out_size, void* d_ws, size_t ws_size,
                              hipStream_t stream) {
  (void)in_sizes; (void)n_in; (void)out_size; (void)ws_size;
  const float* x    = (const float*)d_in[0];
  const float* cosT = (const float*)d_in[1];
  const float* sinT = (const float*)d_in[2];
  const float* Wq   = (const float*)d_in[3];
  const float* Wk   = (const float*)d_in[4];
  const float* Wv   = (const float*)d_in[5];
  const float* Wo   = (const float*)d_in[6];
  float* out = (float*)d_out;

  char* ws = (char*)d_ws;
  size_t off = 0;
  auto take = [&](size_t bytes) { char* p = ws + off; off += (bytes + 255) & ~(size_t)255; return p; };

  bf16_t* xb    = (bf16_t*)take((size_t)Mc * Cdim * 2);      // reused as attn-out
  bf16_t* Wqkvt = (bf16_t*)take((size_t)Nqkv * Cdim * 2);    // [3072][2048]
  bf16_t* Wot   = (bf16_t*)take((size_t)Cdim * (Hc * HDc) * 2);
  bf16_t* Qp    = (bf16_t*)take((size_t)Mc * (Hc * HDc) * 2);
  bf16_t* Kp    = (bf16_t*)take((size_t)Mc * (KVc * HDc) * 2);
  bf16_t* Vt    = (bf16_t*)take((size_t)Mc * (KVc * HDc) * 2);
  bf16_t* Wqt = Wqkvt;
  bf16_t* Wkt = Wqkvt + (size_t)2048 * Cdim;
  bf16_t* Wvt = Wqkvt + (size_t)2560 * Cdim;
  bf16_t* attn = xb;   // xb dead after QKV projection

  // 1. prep: convert x + transpose-convert all weights (one launch)
  k_prep<<<dim3(4096 + 1024 + 256 + 256 + 1024), dim3(256), 0, stream>>>(
      x, xb, Wq, Wk, Wv, Wo, Wqt, Wkt, Wvt, Wot);
  // 2. fused QKV projection + RoPE + repack + V-transpose (768 blocks, 3/CU)
  k_gemm_qkv<<<dim3(Nqkv / 128, Mc / 128), dim3(256), 0, stream>>>(
      xb, Wqkvt, cosT, sinT, Qp, Kp, Vt);
  // 3. attention: 256 blocks x 512 threads, kvh-grouped XCD mapping
  k_attn<<<dim3(256), dim3(512), 0, stream>>>(Qp, Kp, Vt, attn);
  // 4. output projection, fp32 out
  k_gemm_bt<<<dim3(Cdim / 128, Mc / 128), dim3(256), 0, stream>>>(
      attn, Wot, out, Mc, Cdim, Hc * HDc);
}

// Round 11
// 284.001 us; speedup vs baseline: 1.0208x; 1.0208x over previous
//
#include <hip/hip_runtime.h>
#include <hip/hip_bf16.h>
#include <math.h>

typedef __bf16 bf16_t;
typedef __bf16 bf16x8 __attribute__((ext_vector_type(8)));
typedef float f32x4 __attribute__((ext_vector_type(4)));

constexpr int Bc = 2, Tc = 2048, Cdim = 2048, Hc = 16, KVc = 4, HDc = 128;
constexpr int Mc = Bc * Tc;      // 4096
constexpr int Nqkv = 3072;       // fused projection width: 2048 Q + 512 K + 512 V

typedef const __attribute__((address_space(1))) void* as1_cptr;
typedef __attribute__((address_space(3))) void* as3_ptr;

__device__ __forceinline__ void gload_lds16(const bf16_t* g, bf16_t* l) {
  __builtin_amdgcn_global_load_lds((as1_cptr)(const void*)g, (as3_ptr)(void*)l, 16, 0, 0);
}

__device__ __forceinline__ unsigned int cvt_pk_bf16(float lo, float hi) {
  unsigned int r;
  asm("v_cvt_pk_bf16_f32 %0, %1, %2" : "=v"(r) : "v"(lo), "v"(hi));
  return r;
}
__device__ __forceinline__ void perm32swap(unsigned int& a, unsigned int& b) {
  asm("v_permlane32_swap_b32 %0, %1" : "+v"(a), "+v"(b));
}
__device__ __forceinline__ void perm16swap(unsigned int& a, unsigned int& b) {
  asm("v_permlane16_swap_b32 %0, %1" : "+v"(a), "+v"(b));
}
// guaranteed single-instruction exp2 (inputs bounded, no denormal concerns)
__device__ __forceinline__ float fast_exp2(float x) {
  float r;
  asm("v_exp_f32 %0, %1" : "=v"(r) : "v"(x));
  return r;
}

// ---------------- prep: x f32->bf16 + 4 weight transpose-converts, 1 launch
// tile padded [64][73] (odd half-stride kills the 16-way transpose conflict)
__global__ void k_prep(const float* __restrict__ x, bf16_t* __restrict__ xb,
                       const float* __restrict__ Wq, const float* __restrict__ Wk,
                       const float* __restrict__ Wv, const float* __restrict__ Wo,
                       bf16_t* __restrict__ Wqt, bf16_t* __restrict__ Wkt,
                       bf16_t* __restrict__ Wvt, bf16_t* __restrict__ Wot) {
  __shared__ bf16_t tile[64][73];
  int bid = blockIdx.x;
  if (bid < 4096) {
    int i = (bid * 256 + threadIdx.x) * 8;
    float4 a = *(const float4*)(x + i);
    float4 b = *(const float4*)(x + i + 4);
    bf16x8 v;
    v[0] = (bf16_t)a.x; v[1] = (bf16_t)a.y; v[2] = (bf16_t)a.z; v[3] = (bf16_t)a.w;
    v[4] = (bf16_t)b.x; v[5] = (bf16_t)b.y; v[6] = (bf16_t)b.z; v[7] = (bf16_t)b.w;
    *(bf16x8*)(xb + i) = v;
    return;
  }
  bid -= 4096;
  const float* W; bf16_t* Wt; int K, N, k0, n0;
  if (bid < 1024)      { W = Wq; Wt = Wqt; K = 2048; N = 2048; k0 = (bid >> 5) * 64; n0 = (bid & 31) * 64; }
  else if (bid < 1280) { bid -= 1024; W = Wk; Wt = Wkt; K = 2048; N = 512; k0 = (bid >> 3) * 64; n0 = (bid & 7) * 64; }
  else if (bid < 1536) { bid -= 1280; W = Wv; Wt = Wvt; K = 2048; N = 512; k0 = (bid >> 3) * 64; n0 = (bid & 7) * 64; }
  else                 { bid -= 1536; W = Wo; Wt = Wot; K = 2048; N = 2048; k0 = (bid >> 5) * 64; n0 = (bid & 31) * 64; }
  const int t = threadIdx.x;
#pragma unroll
  for (int i = 0; i < 4; ++i) {
    int idx = t + i * 256;
    int r = idx >> 4;
    int c4 = (idx & 15) * 4;
    float4 v = *(const float4*)(W + (size_t)(k0 + r) * N + n0 + c4);
    tile[r][c4 + 0] = (bf16_t)v.x; tile[r][c4 + 1] = (bf16_t)v.y;
    tile[r][c4 + 2] = (bf16_t)v.z; tile[r][c4 + 3] = (bf16_t)v.w;
  }
  __syncthreads();
#pragma unroll
  for (int i = 0; i < 4; ++i) {
    int idx = t + i * 256;
    int n = idx >> 4;
    int kc = (idx & 15) * 4;
    alignas(8) bf16_t o[4];
#pragma unroll
    for (int j = 0; j < 4; ++j) o[j] = tile[kc + j][n];
    *(uint2*)(Wt + (size_t)(n0 + n) * K + k0 + kc) = *(uint2*)o;
  }
}

// ---------------- GEMM: C[M,N] = A[M,K] * Bt[N,K]^T (fp32 out, O-proj) ----
__global__ __launch_bounds__(256, 2) void k_gemm_bt(
    const bf16_t* __restrict__ A, const bf16_t* __restrict__ Bt,
    float* __restrict__ Cout, int M, int N, int K) {
  __shared__ alignas(16) bf16_t Ash[128 * 64];
  __shared__ alignas(16) bf16_t Bsh[128 * 64];
  const int tid = threadIdx.x;
  const int wave = tid >> 6, lane = tid & 63;
  const int col = lane & 15, quad = lane >> 4;
  const int gx = gridDim.x;
  const int nwg = gx * gridDim.y;
  int wg = blockIdx.y * gx + blockIdx.x;
  if ((nwg & 7) == 0) wg = (wg & 7) * (nwg >> 3) + (wg >> 3);
  const int m0 = (wg / gx) * 128, n0 = (wg % gx) * 128;
  const int wr = wave >> 1, wc = wave & 1;

  f32x4 acc[4][4];
#pragma unroll
  for (int i = 0; i < 4; ++i)
#pragma unroll
    for (int j = 0; j < 4; ++j) acc[i][j] = f32x4{0.f, 0.f, 0.f, 0.f};

  const int lrow = lane >> 3;
  const int lkc8 = (lane & 7) ^ lrow;

  for (int k0 = 0; k0 < K; k0 += 64) {
    __syncthreads();
#pragma unroll
    for (int i = 0; i < 4; ++i) {
      const int rb = wave * 32 + i * 8;
      gload_lds16(A + (size_t)(m0 + rb + lrow) * K + k0 + lkc8 * 8, Ash + rb * 64);
      gload_lds16(Bt + (size_t)(n0 + rb + lrow) * K + k0 + lkc8 * 8, Bsh + rb * 64);
    }
    __syncthreads();
#pragma unroll
    for (int kc = 0; kc < 2; ++kc) {
      bf16x8 af[4], bfr[4];
#pragma unroll
      for (int mt = 0; mt < 4; ++mt) {
        const int m = wr * 64 + mt * 16 + col;
        const int slot = (kc * 4 + quad) ^ (m & 7);
        af[mt] = *(const bf16x8*)(Ash + m * 64 + slot * 8);
      }
#pragma unroll
      for (int nt = 0; nt < 4; ++nt) {
        const int n = wc * 64 + nt * 16 + col;
        const int slot = (kc * 4 + quad) ^ (n & 7);
        bfr[nt] = *(const bf16x8*)(Bsh + n * 64 + slot * 8);
      }
#pragma unroll
      for (int mt = 0; mt < 4; ++mt)
#pragma unroll
        for (int nt = 0; nt < 4; ++nt)
          acc[mt][nt] = __builtin_amdgcn_mfma_f32_16x16x32_bf16(
              af[mt], bfr[nt], acc[mt][nt], 0, 0, 0);
    }
  }
#pragma unroll
  for (int mt = 0; mt < 4; ++mt)
#pragma unroll
    for (int i = 0; i < 4; ++i) {
      const int row = m0 + wr * 64 + mt * 16 + quad * 4 + i;
#pragma unroll
      for (int nt = 0; nt < 4; ++nt)
        Cout[(size_t)row * N + n0 + wc * 64 + nt * 16 + col] = acc[mt][nt][i];
    }
}

// ---------------- fused QKV GEMM + RoPE + head-repack + V-transpose ------
__global__ __launch_bounds__(256, 3) void k_gemm_qkv(
    const bf16_t* __restrict__ A, const bf16_t* __restrict__ Bt,
    const float* __restrict__ cs, const float* __restrict__ sn,
    bf16_t* __restrict__ Qp, bf16_t* __restrict__ Kp, bf16_t* __restrict__ Vt) {
  constexpr int K = Cdim;
  __shared__ alignas(16) bf16_t Ash[128 * 64];
  __shared__ alignas(16) bf16_t Bsh[128 * 64];
  const int tid = threadIdx.x;
  const int wave = tid >> 6, lane = tid & 63;
  const int col = lane & 15, quad = lane >> 4;
  const int gx = gridDim.x;
  const int nwg = gx * gridDim.y;
  int wg = blockIdx.y * gx + blockIdx.x;
  wg = (wg & 7) * (nwg >> 3) + (wg >> 3);
  const int m0 = (wg / gx) * 128;
  const int bxi = wg % gx;
  const int n0 = bxi * 128;

  f32x4 acc[2][8];
#pragma unroll
  for (int i = 0; i < 2; ++i)
#pragma unroll
    for (int j = 0; j < 8; ++j) acc[i][j] = f32x4{0.f, 0.f, 0.f, 0.f};

  const int lrow = lane >> 3;
  const int lkc8 = (lane & 7) ^ lrow;

  for (int k0 = 0; k0 < K; k0 += 64) {
    __syncthreads();
#pragma unroll
    for (int i = 0; i < 4; ++i) {
      const int rb = wave * 32 + i * 8;
      gload_lds16(A + (size_t)(m0 + rb + lrow) * K + k0 + lkc8 * 8, Ash + rb * 64);
      gload_lds16(Bt + (size_t)(n0 + rb + lrow) * K + k0 + lkc8 * 8, Bsh + rb * 64);
    }
    __syncthreads();
#pragma unroll
    for (int kc = 0; kc < 2; ++kc) {
      bf16x8 af[2], bfr[8];
#pragma unroll
      for (int mt = 0; mt < 2; ++mt) {
        const int m = wave * 32 + mt * 16 + col;
        const int slot = (kc * 4 + quad) ^ (m & 7);
        af[mt] = *(const bf16x8*)(Ash + m * 64 + slot * 8);
      }
#pragma unroll
      for (int nt = 0; nt < 8; ++nt) {
        const int n = nt * 16 + col;
        const int slot = (kc * 4 + quad) ^ (n & 7);
        bfr[nt] = *(const bf16x8*)(Bsh + n * 64 + slot * 8);
      }
#pragma unroll
      for (int mt = 0; mt < 2; ++mt)
#pragma unroll
        for (int nt = 0; nt < 8; ++nt)
          acc[mt][nt] = __builtin_amdgcn_mfma_f32_16x16x32_bf16(
              af[mt], bfr[nt], acc[mt][nt], 0, 0, 0);
    }
  }

  const int bx = bxi;   // head-tile: 0-15 Q, 16-19 K, 20-23 V
  if (bx < 20) {
    const bool isQ = bx < 16;
#pragma unroll
    for (int mt = 0; mt < 2; ++mt)
#pragma unroll
      for (int i = 0; i < 4; ++i) {
        const int row = m0 + wave * 32 + mt * 16 + quad * 4 + i;
        const int b = row >> 11, t = row & (Tc - 1);
        bf16_t* op = isQ ? Qp + ((size_t)(b * Hc + bx) * Tc + t) * HDc
                         : Kp + ((size_t)(b * KVc + (bx - 16)) * Tc + t) * HDc;
        const float* cr = cs + t * HDc;
        const float* sr = sn + t * HDc;
#pragma unroll
        for (int nt = 0; nt < 4; ++nt) {
          const int d = nt * 16 + col;
          const float c = cr[d], s = sr[d];
          const float x0 = acc[mt][nt][i], x1 = acc[mt][nt + 4][i];
          op[d]      = (bf16_t)(x0 * c - x1 * s);
          op[d + 64] = (bf16_t)(x1 * c + x0 * s);
        }
      }
  } else {
    const int kv = bx - 20;
#pragma unroll
    for (int mt = 0; mt < 2; ++mt) {
      const int row0 = m0 + wave * 32 + mt * 16 + quad * 4;
      const int b = row0 >> 11, t0 = row0 & (Tc - 1);
#pragma unroll
      for (int nt = 0; nt < 8; ++nt) {
        const int d = nt * 16 + col;
        alignas(8) bf16_t o[4];
#pragma unroll
        for (int i = 0; i < 4; ++i) o[i] = (bf16_t)acc[mt][nt][i];
        *(uint2*)(Vt + ((size_t)(b * KVc + kv) * HDc + d) * Tc + t0) = *(uint2*)o;
      }
    }
  }
}

// ---------------- Flash attention v13: v12 pipeline, spill-free ----------
// v12's regression was pure VGPR spill: LDS (130KB) pins occupancy at
// 1 block/CU, but __launch_bounds__(512,2) capped VGPRs at 128 as if 2
// blocks could fit -> ~50 regs spilled to scratch (WRITE_SIZE 16->33MB).
// (512,1) lifts the cap to 256 with IDENTICAL occupancy. T15 pipeline
// (QK(r)+PV(r-1) fused MFMA cluster, exp/pack latency crosses the region
// boundary) now runs register-resident.
__global__ __launch_bounds__(512, 1) void k_attn(
    const bf16_t* __restrict__ Qp, const bf16_t* __restrict__ Kp,
    const bf16_t* __restrict__ Vt, bf16_t* __restrict__ Oout) {
  constexpr float sc2 = 0.08838834764831845f * 1.4426950408889634f; // scale*log2(e)
  __shared__ alignas(16) bf16_t Ksh[2][2][64 * 128];  // [buf][parity], swz ^(r&7)
  __shared__ alignas(16) bf16_t Vsh[2][2][128 * 64];  // [buf][parity], swz ^(d&7)
  __shared__ float lex[4][64][2];                     // l exchange

  const int wg = blockIdx.x;
  const int g = wg & 7, kslot = wg >> 3;
  const int kvh = g & 3, b = g >> 2;
  const int h = kvh * 4 + (kslot >> 3);
  const int i2 = kslot & 7;

  const int tid = threadIdx.x, wave = tid >> 6, lane = tid & 63;
  const int wq = wave & 3, wk = wave >> 2;
  const int col = lane & 15, quad = lane >> 4;

  const bf16_t* Kb = Kp + (size_t)(b * KVc + kvh) * Tc * HDc;
  const bf16_t* Vb = Vt + (size_t)(b * KVc + kvh) * HDc * Tc;
  const bf16_t* Qbh = Qp + (size_t)(b * Hc + h) * Tc * HDc;

  const int st_kr = lane >> 4, st_kc8 = lane & 15;
  const int st_vr = lane >> 3, st_vc8 = lane & 7;

  const int qt0 = 15 - i2, qt1 = i2;
  const int PT0 = qt0 + 1;     // tiles in pass 0; 17 tiles total (s=0..16)

  const int q0p0 = qt0 * 128 + wq * 32;
  const int q0p1 = qt1 * 128 + wq * 32;
  int q0 = q0p0;

  // preload BOTH passes' Q fragments (removes boundary reload latency)
  bf16x8 qA0[4], qB0[4], qA1[4], qB1[4];
  {
    const bf16_t* a0 = Qbh + (size_t)(q0p0 + col) * HDc;
    const bf16_t* b0 = Qbh + (size_t)(q0p0 + 16 + col) * HDc;
    const bf16_t* a1 = Qbh + (size_t)(q0p1 + col) * HDc;
    const bf16_t* b1 = Qbh + (size_t)(q0p1 + 16 + col) * HDc;
#pragma unroll
    for (int kc = 0; kc < 4; ++kc) {
      bf16x8 r0 = *(const bf16x8*)(a0 + kc * 32 + quad * 8);
      bf16x8 r1 = *(const bf16x8*)(b0 + kc * 32 + quad * 8);
      bf16x8 r2 = *(const bf16x8*)(a1 + kc * 32 + quad * 8);
      bf16x8 r3 = *(const bf16x8*)(b1 + kc * 32 + quad * 8);
#pragma unroll
      for (int e = 0; e < 8; ++e) {
        qA0[kc][e] = (bf16_t)((float)r0[e] * sc2);
        qB0[kc][e] = (bf16_t)((float)r1[e] * sc2);
        qA1[kc][e] = (bf16_t)((float)r2[e] * sc2);
        qB1[kc][e] = (bf16_t)((float)r3[e] * sc2);
      }
    }
  }

  f32x4 oA[8], oB[8];
#pragma unroll
  for (int nb = 0; nb < 8; ++nb) {
    oA[nb] = f32x4{0.f, 0.f, 0.f, 0.f};
    oB[nb] = f32x4{0.f, 0.f, 0.f, 0.f};
  }
  float lA = 0.f, lB = 0.f;
  unsigned int pwA[4][2], pwB[4][2];   // saved P of tile r (consumed r+1)

  auto kvb_of = [&](int t) { const int tn = (t < PT0) ? t : t - PT0; return tn * 128 + wk * 64; };

  auto stageK = [&](int t) {
    bf16_t* Kd = &Ksh[t & 1][wk][0];
    const int kb = kvb_of(t);
#pragma unroll
    for (int i = 0; i < 4; ++i) {
      const int rb = wq * 16 + i * 4;
      const int r = rb + st_kr;
      const int kc8 = st_kc8 ^ (r & 7);
      gload_lds16(Kb + (size_t)(kb + r) * HDc + kc8 * 8, Kd + rb * 128);
    }
  };
  auto stageV = [&](int t) {
    bf16_t* Vd = &Vsh[t & 1][wk][0];
    const int kb = kvb_of(t);
#pragma unroll
    for (int i = 0; i < 4; ++i) {
      const int db = wq * 32 + i * 8;
      const int d = db + st_vr;
      const int tc8 = st_vc8 ^ (d & 7);
      gload_lds16(Vb + (size_t)d * Tc + kb + tc8 * 8, Vd + db * 64);
    }
  };

  auto qkc = [&](const bf16x8 (&qa)[4], const bf16x8 (&qb)[4],
                 f32x4 (&sA)[4], f32x4 (&sB)[4], const bf16_t* Kc) {
#pragma unroll
    for (int kc = 0; kc < 4; ++kc)
#pragma unroll
      for (int tb = 0; tb < 4; ++tb) {
        const int rr = tb * 16 + col;
        const int slot = (kc * 4 + quad) ^ (rr & 7);
        bf16x8 kf = *(const bf16x8*)(Kc + rr * 128 + slot * 8);
        sA[tb] = __builtin_amdgcn_mfma_f32_16x16x32_bf16(kf, qa[kc], sA[tb], 0, 0, 0);
        sB[tb] = __builtin_amdgcn_mfma_f32_16x16x32_bf16(kf, qb[kc], sB[tb], 0, 0, 0);
      }
  };

  auto pvc = [&](const bf16_t* Vc) {
#pragma unroll
    for (int kc = 0; kc < 2; ++kc) {
      unsigned int a0 = pwA[2 * kc][0], c0 = pwA[2 * kc + 1][0];
      unsigned int a1 = pwA[2 * kc][1], c1 = pwA[2 * kc + 1][1];
      perm32swap(a0, c0); perm32swap(a1, c1);
      perm16swap(a0, c0); perm16swap(a1, c1);
      union { unsigned int w[4]; bf16x8 v; } uA;
      uA.w[0] = a0; uA.w[1] = a1; uA.w[2] = c0; uA.w[3] = c1;
      unsigned int d0 = pwB[2 * kc][0], e0 = pwB[2 * kc + 1][0];
      unsigned int d1 = pwB[2 * kc][1], e1 = pwB[2 * kc + 1][1];
      perm32swap(d0, e0); perm32swap(d1, e1);
      perm16swap(d0, e0); perm16swap(d1, e1);
      union { unsigned int w[4]; bf16x8 v; } uB;
      uB.w[0] = d0; uB.w[1] = d1; uB.w[2] = e0; uB.w[3] = e1;
      const bf16x8 pfA = uA.v, pfB = uB.v;
#pragma unroll
      for (int nb = 0; nb < 8; ++nb) {
        const int d = nb * 16 + col;
        const int vslot = (kc * 4 + quad) ^ (d & 7);
        bf16x8 vf = *(const bf16x8*)(Vc + d * 64 + vslot * 8);
        oA[nb] = __builtin_amdgcn_mfma_f32_16x16x32_bf16(pfA, vf, oA[nb], 0, 0, 0);
        oB[nb] = __builtin_amdgcn_mfma_f32_16x16x32_bf16(pfB, vf, oB[nb], 0, 0, 0);
      }
    }
  };

  auto expp = [&](const f32x4 (&sA)[4], const f32x4 (&sB)[4], int kb, bool diag) {
    const int qrA = q0 + col, qrB = q0 + 16 + col;
#pragma unroll
    for (int tb = 0; tb < 4; ++tb) {
      const int kvb = kb + tb * 16 + quad * 4;
      float a0 = fast_exp2(sA[tb][0]), a1 = fast_exp2(sA[tb][1]);
      float a2 = fast_exp2(sA[tb][2]), a3 = fast_exp2(sA[tb][3]);
      float b0 = fast_exp2(sB[tb][0]), b1 = fast_exp2(sB[tb][1]);
      float b2 = fast_exp2(sB[tb][2]), b3 = fast_exp2(sB[tb][3]);
      if (diag) {
        a0 = (kvb + 0 > qrA) ? 0.f : a0;
        a1 = (kvb + 1 > qrA) ? 0.f : a1;
        a2 = (kvb + 2 > qrA) ? 0.f : a2;
        a3 = (kvb + 3 > qrA) ? 0.f : a3;
        b0 = (kvb + 0 > qrB) ? 0.f : b0;
        b1 = (kvb + 1 > qrB) ? 0.f : b1;
        b2 = (kvb + 2 > qrB) ? 0.f : b2;
        b3 = (kvb + 3 > qrB) ? 0.f : b3;
      }
      lA += (a0 + a1) + (a2 + a3);
      lB += (b0 + b1) + (b2 + b3);
      pwA[tb][0] = cvt_pk_bf16(a0, a1);
      pwA[tb][1] = cvt_pk_bf16(a2, a3);
      pwB[tb][0] = cvt_pk_bf16(b0, b1);
      pwB[tb][1] = cvt_pk_bf16(b2, b3);
    }
  };

  // two-half parity merge through a dead 32KB V buffer + O write
  auto combine = [&](float* dead, int q0o) {
    float* xo = dead + wq * 2048;
    asm volatile("s_barrier" ::: "memory");
    if (wk) {
#pragma unroll
      for (int nb = 0; nb < 8; ++nb) *(f32x4*)(xo + nb * 256 + lane * 4) = oA[nb];
      lex[wq][lane][0] = lA;
      lex[wq][lane][1] = lB;
    }
    asm volatile("s_waitcnt lgkmcnt(0)" ::: "memory");
    asm volatile("s_barrier" ::: "memory");
    if (!wk) {
#pragma unroll
      for (int nb = 0; nb < 8; ++nb) oA[nb] += *(const f32x4*)(xo + nb * 256 + lane * 4);
    }
    asm volatile("s_barrier" ::: "memory");
    if (wk) {
#pragma unroll
      for (int nb = 0; nb < 8; ++nb) *(f32x4*)(xo + nb * 256 + lane * 4) = oB[nb];
    }
    asm volatile("s_waitcnt lgkmcnt(0)" ::: "memory");
    asm volatile("s_barrier" ::: "memory");
    if (!wk) {
#pragma unroll
      for (int nb = 0; nb < 8; ++nb) oB[nb] += *(const f32x4*)(xo + nb * 256 + lane * 4);
      const float fA = lA + lex[wq][lane][0];
      const float fB = lB + lex[wq][lane][1];
#pragma unroll
      for (int gg = 0; gg < 2; ++gg) {
        float rs = gg ? fB : fA;
        rs += __shfl_xor(rs, 16);
        rs += __shfl_xor(rs, 32);
        const float inv = 1.0f / rs;
        const f32x4* oa = gg ? oB : oA;
        const int qbase = q0o + gg * 16;
#pragma unroll
        for (int i = 0; i < 4; ++i) {
          const float iq = __shfl(inv, quad * 4 + i);
          const int qrow = qbase + quad * 4 + i;
          bf16_t* op = Oout + ((size_t)(b * Tc) + qrow) * (Hc * HDc) + h * HDc;
#pragma unroll
          for (int nb = 0; nb < 8; ++nb) op[nb * 16 + col] = (bf16_t)(oa[nb][i] * iq);
        }
      }
    }
  };

  // prologue: K(0) + V(0) in flight (8 loads -> uniform vmcnt(8) at r=0)
  stageK(0); stageV(0);

#pragma unroll 1
  for (int r = 0; r <= 16; ++r) {
    asm volatile("s_barrier" ::: "memory");
    stageK(r < 16 ? r + 1 : 16);   // K one region ahead (dup at r=16 benign)
    stageV(r);                     // V consumed next region (dup at r=0 benign)
    asm volatile("s_waitcnt vmcnt(8)" ::: "memory");
    asm volatile("s_barrier" ::: "memory");

    f32x4 stA[4], stB[4];
#pragma unroll
    for (int tb = 0; tb < 4; ++tb) {
      stA[tb] = f32x4{0.f, 0.f, 0.f, 0.f};
      stB[tb] = f32x4{0.f, 0.f, 0.f, 0.f};
    }
    const bf16_t* Kc = &Ksh[r & 1][wk][0];
    __builtin_amdgcn_s_setprio(1);
    if (r < PT0) qkc(qA0, qB0, stA, stB, Kc);
    else         qkc(qA1, qB1, stA, stB, Kc);
    if (r >= 1)  pvc(&Vsh[(r - 1) & 1][wk][0]);   // deferred PV of tile r-1
    __builtin_amdgcn_s_setprio(0);

    if (r == PT0) {   // pass-0 accumulators complete (PV(PT0-1) just done)
      combine((float*)&Vsh[(PT0 - 1) & 1][0][0], q0);
#pragma unroll
      for (int nb = 0; nb < 8; ++nb) {
        oA[nb] = f32x4{0.f, 0.f, 0.f, 0.f};
        oB[nb] = f32x4{0.f, 0.f, 0.f, 0.f};
      }
      lA = 0.f; lB = 0.f;
      q0 = q0p1;
    }

    const bool diag = (r == PT0 - 1) || (r == 16);
    expp(stA, stB, kvb_of(r), diag);   // P for tile r -> consumed region r+1
  }

  // epilogue region: PV(16) + pass-1 merge
  asm volatile("s_barrier" ::: "memory");
  asm volatile("s_waitcnt vmcnt(0)" ::: "memory");
  asm volatile("s_barrier" ::: "memory");
  __builtin_amdgcn_s_setprio(1);
  pvc(&Vsh[0][wk][0]);                 // V(16) is in buffer 0
  __builtin_amdgcn_s_setprio(0);
  combine((float*)&Vsh[1][0][0], q0);  // buffer 1 (V(15)) is dead
}

// ---------------- launch ----------------
extern "C" void kernel_launch(void* const* d_in, const int* in_sizes, int n_in,
                              void* d_out, int out_size, void* d_ws, size_t ws_size,
                              hipStream_t stream) {
  (void)in_sizes; (void)n_in; (void)out_size; (void)ws_size;
  const float* x    = (const float*)d_in[0];
  const float* cosT = (const float*)d_in[1];
  const float* sinT = (const float*)d_in[2];
  const float* Wq   = (const float*)d_in[3];
  const float* Wk   = (const float*)d_in[4];
  const float* Wv   = (const float*)d_in[5];
  const float* Wo   = (const float*)d_in[6];
  float* out = (float*)d_out;

  char* ws = (char*)d_ws;
  size_t off = 0;
  auto take = [&](size_t bytes) { char* p = ws + off; off += (bytes + 255) & ~(size_t)255; return p; };

  bf16_t* xb    = (bf16_t*)take((size_t)Mc * Cdim * 2);      // reused as attn-out
  bf16_t* Wqkvt = (bf16_t*)take((size_t)Nqkv * Cdim * 2);    // [3072][2048]
  bf16_t* Wot   = (bf16_t*)take((size_t)Cdim * (Hc * HDc) * 2);
  bf16_t* Qp    = (bf16_t*)take((size_t)Mc * (Hc * HDc) * 2);
  bf16_t* Kp    = (bf16_t*)take((size_t)Mc * (KVc * HDc) * 2);
  bf16_t* Vt    = (bf16_t*)take((size_t)Mc * (KVc * HDc) * 2);
  bf16_t* Wqt = Wqkvt;
  bf16_t* Wkt = Wqkvt + (size_t)2048 * Cdim;
  bf16_t* Wvt = Wqkvt + (size_t)2560 * Cdim;
  bf16_t* attn = xb;   // xb dead after QKV projection

  // 1. prep: convert x + transpose-convert all weights (one launch)
  k_prep<<<dim3(4096 + 1024 + 256 + 256 + 1024), dim3(256), 0, stream>>>(
      x, xb, Wq, Wk, Wv, Wo, Wqt, Wkt, Wvt, Wot);
  // 2. fused QKV projection + RoPE + repack + V-transpose (768 blocks, 3/CU)
  k_gemm_qkv<<<dim3(Nqkv / 128, Mc / 128), dim3(256), 0, stream>>>(
      xb, Wqkvt, cosT, sinT, Qp, Kp, Vt);
  // 3. attention: 256 blocks x 512 threads, kvh-grouped XCD mapping
  k_attn<<<dim3(256), dim3(512), 0, stream>>>(Qp, Kp, Vt, attn);
  // 4. output projection, fp32 out
  k_gemm_bt<<<dim3(Cdim / 128, Mc / 128), dim3(256), 0, stream>>>(
      attn, Wot, out, Mc, Cdim, Hc * HDc);
}

// Round 12
// 277.004 us; speedup vs baseline: 1.0466x; 1.0253x over previous
//
#include <hip/hip_runtime.h>
#include <hip/hip_bf16.h>
#include <math.h>

typedef __bf16 bf16_t;
typedef __bf16 bf16x8 __attribute__((ext_vector_type(8)));
typedef float f32x4 __attribute__((ext_vector_type(4)));

constexpr int Bc = 2, Tc = 2048, Cdim = 2048, Hc = 16, KVc = 4, HDc = 128;
constexpr int Mc = Bc * Tc;      // 4096
constexpr int Nqkv = 3072;       // fused projection width: 2048 Q + 512 K + 512 V

typedef const __attribute__((address_space(1))) void* as1_cptr;
typedef __attribute__((address_space(3))) void* as3_ptr;

__device__ __forceinline__ void gload_lds16(const bf16_t* g, bf16_t* l) {
  __builtin_amdgcn_global_load_lds((as1_cptr)(const void*)g, (as3_ptr)(void*)l, 16, 0, 0);
}

__device__ __forceinline__ unsigned int cvt_pk_bf16(float lo, float hi) {
  unsigned int r;
  asm("v_cvt_pk_bf16_f32 %0, %1, %2" : "=v"(r) : "v"(lo), "v"(hi));
  return r;
}
__device__ __forceinline__ void perm32swap(unsigned int& a, unsigned int& b) {
  asm("v_permlane32_swap_b32 %0, %1" : "+v"(a), "+v"(b));
}
__device__ __forceinline__ void perm16swap(unsigned int& a, unsigned int& b) {
  asm("v_permlane16_swap_b32 %0, %1" : "+v"(a), "+v"(b));
}
// guaranteed single-instruction exp2 (inputs bounded, no denormal concerns)
__device__ __forceinline__ float fast_exp2(float x) {
  float r;
  asm("v_exp_f32 %0, %1" : "=v"(r) : "v"(x));
  return r;
}

// ---------------- prep: x f32->bf16 + 4 weight transpose-converts, 1 launch
// tile padded [64][73] (odd half-stride kills the 16-way transpose conflict)
__global__ void k_prep(const float* __restrict__ x, bf16_t* __restrict__ xb,
                       const float* __restrict__ Wq, const float* __restrict__ Wk,
                       const float* __restrict__ Wv, const float* __restrict__ Wo,
                       bf16_t* __restrict__ Wqt, bf16_t* __restrict__ Wkt,
                       bf16_t* __restrict__ Wvt, bf16_t* __restrict__ Wot) {
  __shared__ bf16_t tile[64][73];
  int bid = blockIdx.x;
  if (bid < 4096) {
    int i = (bid * 256 + threadIdx.x) * 8;
    float4 a = *(const float4*)(x + i);
    float4 b = *(const float4*)(x + i + 4);
    bf16x8 v;
    v[0] = (bf16_t)a.x; v[1] = (bf16_t)a.y; v[2] = (bf16_t)a.z; v[3] = (bf16_t)a.w;
    v[4] = (bf16_t)b.x; v[5] = (bf16_t)b.y; v[6] = (bf16_t)b.z; v[7] = (bf16_t)b.w;
    *(bf16x8*)(xb + i) = v;
    return;
  }
  bid -= 4096;
  const float* W; bf16_t* Wt; int K, N, k0, n0;
  if (bid < 1024)      { W = Wq; Wt = Wqt; K = 2048; N = 2048; k0 = (bid >> 5) * 64; n0 = (bid & 31) * 64; }
  else if (bid < 1280) { bid -= 1024; W = Wk; Wt = Wkt; K = 2048; N = 512; k0 = (bid >> 3) * 64; n0 = (bid & 7) * 64; }
  else if (bid < 1536) { bid -= 1280; W = Wv; Wt = Wvt; K = 2048; N = 512; k0 = (bid >> 3) * 64; n0 = (bid & 7) * 64; }
  else                 { bid -= 1536; W = Wo; Wt = Wot; K = 2048; N = 2048; k0 = (bid >> 5) * 64; n0 = (bid & 31) * 64; }
  const int t = threadIdx.x;
#pragma unroll
  for (int i = 0; i < 4; ++i) {
    int idx = t + i * 256;
    int r = idx >> 4;
    int c4 = (idx & 15) * 4;
    float4 v = *(const float4*)(W + (size_t)(k0 + r) * N + n0 + c4);
    tile[r][c4 + 0] = (bf16_t)v.x; tile[r][c4 + 1] = (bf16_t)v.y;
    tile[r][c4 + 2] = (bf16_t)v.z; tile[r][c4 + 3] = (bf16_t)v.w;
  }
  __syncthreads();
#pragma unroll
  for (int i = 0; i < 4; ++i) {
    int idx = t + i * 256;
    int n = idx >> 4;
    int kc = (idx & 15) * 4;
    alignas(8) bf16_t o[4];
#pragma unroll
    for (int j = 0; j < 4; ++j) o[j] = tile[kc + j][n];
    *(uint2*)(Wt + (size_t)(n0 + n) * K + k0 + kc) = *(uint2*)o;
  }
}

// ---------------- GEMM: C[M,N] = A[M,K] * Bt[N,K]^T (fp32 out, O-proj) ----
__global__ __launch_bounds__(256, 2) void k_gemm_bt(
    const bf16_t* __restrict__ A, const bf16_t* __restrict__ Bt,
    float* __restrict__ Cout, int M, int N, int K) {
  __shared__ alignas(16) bf16_t Ash[128 * 64];
  __shared__ alignas(16) bf16_t Bsh[128 * 64];
  const int tid = threadIdx.x;
  const int wave = tid >> 6, lane = tid & 63;
  const int col = lane & 15, quad = lane >> 4;
  const int gx = gridDim.x;
  const int nwg = gx * gridDim.y;
  int wg = blockIdx.y * gx + blockIdx.x;
  if ((nwg & 7) == 0) wg = (wg & 7) * (nwg >> 3) + (wg >> 3);
  const int m0 = (wg / gx) * 128, n0 = (wg % gx) * 128;
  const int wr = wave >> 1, wc = wave & 1;

  f32x4 acc[4][4];
#pragma unroll
  for (int i = 0; i < 4; ++i)
#pragma unroll
    for (int j = 0; j < 4; ++j) acc[i][j] = f32x4{0.f, 0.f, 0.f, 0.f};

  const int lrow = lane >> 3;
  const int lkc8 = (lane & 7) ^ lrow;

  for (int k0 = 0; k0 < K; k0 += 64) {
    __syncthreads();
#pragma unroll
    for (int i = 0; i < 4; ++i) {
      const int rb = wave * 32 + i * 8;
      gload_lds16(A + (size_t)(m0 + rb + lrow) * K + k0 + lkc8 * 8, Ash + rb * 64);
      gload_lds16(Bt + (size_t)(n0 + rb + lrow) * K + k0 + lkc8 * 8, Bsh + rb * 64);
    }
    __syncthreads();
#pragma unroll
    for (int kc = 0; kc < 2; ++kc) {
      bf16x8 af[4], bfr[4];
#pragma unroll
      for (int mt = 0; mt < 4; ++mt) {
        const int m = wr * 64 + mt * 16 + col;
        const int slot = (kc * 4 + quad) ^ (m & 7);
        af[mt] = *(const bf16x8*)(Ash + m * 64 + slot * 8);
      }
#pragma unroll
      for (int nt = 0; nt < 4; ++nt) {
        const int n = wc * 64 + nt * 16 + col;
        const int slot = (kc * 4 + quad) ^ (n & 7);
        bfr[nt] = *(const bf16x8*)(Bsh + n * 64 + slot * 8);
      }
#pragma unroll
      for (int mt = 0; mt < 4; ++mt)
#pragma unroll
        for (int nt = 0; nt < 4; ++nt)
          acc[mt][nt] = __builtin_amdgcn_mfma_f32_16x16x32_bf16(
              af[mt], bfr[nt], acc[mt][nt], 0, 0, 0);
    }
  }
#pragma unroll
  for (int mt = 0; mt < 4; ++mt)
#pragma unroll
    for (int i = 0; i < 4; ++i) {
      const int row = m0 + wr * 64 + mt * 16 + quad * 4 + i;
#pragma unroll
      for (int nt = 0; nt < 4; ++nt)
        Cout[(size_t)row * N + n0 + wc * 64 + nt * 16 + col] = acc[mt][nt][i];
    }
}

// ---------------- fused QKV GEMM + RoPE + head-repack + V-transpose ------
__global__ __launch_bounds__(256, 3) void k_gemm_qkv(
    const bf16_t* __restrict__ A, const bf16_t* __restrict__ Bt,
    const float* __restrict__ cs, const float* __restrict__ sn,
    bf16_t* __restrict__ Qp, bf16_t* __restrict__ Kp, bf16_t* __restrict__ Vt) {
  constexpr int K = Cdim;
  __shared__ alignas(16) bf16_t Ash[128 * 64];
  __shared__ alignas(16) bf16_t Bsh[128 * 64];
  const int tid = threadIdx.x;
  const int wave = tid >> 6, lane = tid & 63;
  const int col = lane & 15, quad = lane >> 4;
  const int gx = gridDim.x;
  const int nwg = gx * gridDim.y;
  int wg = blockIdx.y * gx + blockIdx.x;
  wg = (wg & 7) * (nwg >> 3) + (wg >> 3);
  const int m0 = (wg / gx) * 128;
  const int bxi = wg % gx;
  const int n0 = bxi * 128;

  f32x4 acc[2][8];
#pragma unroll
  for (int i = 0; i < 2; ++i)
#pragma unroll
    for (int j = 0; j < 8; ++j) acc[i][j] = f32x4{0.f, 0.f, 0.f, 0.f};

  const int lrow = lane >> 3;
  const int lkc8 = (lane & 7) ^ lrow;

  for (int k0 = 0; k0 < K; k0 += 64) {
    __syncthreads();
#pragma unroll
    for (int i = 0; i < 4; ++i) {
      const int rb = wave * 32 + i * 8;
      gload_lds16(A + (size_t)(m0 + rb + lrow) * K + k0 + lkc8 * 8, Ash + rb * 64);
      gload_lds16(Bt + (size_t)(n0 + rb + lrow) * K + k0 + lkc8 * 8, Bsh + rb * 64);
    }
    __syncthreads();
#pragma unroll
    for (int kc = 0; kc < 2; ++kc) {
      bf16x8 af[2], bfr[8];
#pragma unroll
      for (int mt = 0; mt < 2; ++mt) {
        const int m = wave * 32 + mt * 16 + col;
        const int slot = (kc * 4 + quad) ^ (m & 7);
        af[mt] = *(const bf16x8*)(Ash + m * 64 + slot * 8);
      }
#pragma unroll
      for (int nt = 0; nt < 8; ++nt) {
        const int n = nt * 16 + col;
        const int slot = (kc * 4 + quad) ^ (n & 7);
        bfr[nt] = *(const bf16x8*)(Bsh + n * 64 + slot * 8);
      }
#pragma unroll
      for (int mt = 0; mt < 2; ++mt)
#pragma unroll
        for (int nt = 0; nt < 8; ++nt)
          acc[mt][nt] = __builtin_amdgcn_mfma_f32_16x16x32_bf16(
              af[mt], bfr[nt], acc[mt][nt], 0, 0, 0);
    }
  }

  const int bx = bxi;   // head-tile: 0-15 Q, 16-19 K, 20-23 V
  if (bx < 20) {
    const bool isQ = bx < 16;
#pragma unroll
    for (int mt = 0; mt < 2; ++mt)
#pragma unroll
      for (int i = 0; i < 4; ++i) {
        const int row = m0 + wave * 32 + mt * 16 + quad * 4 + i;
        const int b = row >> 11, t = row & (Tc - 1);
        bf16_t* op = isQ ? Qp + ((size_t)(b * Hc + bx) * Tc + t) * HDc
                         : Kp + ((size_t)(b * KVc + (bx - 16)) * Tc + t) * HDc;
        const float* cr = cs + t * HDc;
        const float* sr = sn + t * HDc;
#pragma unroll
        for (int nt = 0; nt < 4; ++nt) {
          const int d = nt * 16 + col;
          const float c = cr[d], s = sr[d];
          const float x0 = acc[mt][nt][i], x1 = acc[mt][nt + 4][i];
          op[d]      = (bf16_t)(x0 * c - x1 * s);
          op[d + 64] = (bf16_t)(x1 * c + x0 * s);
        }
      }
  } else {
    const int kv = bx - 20;
#pragma unroll
    for (int mt = 0; mt < 2; ++mt) {
      const int row0 = m0 + wave * 32 + mt * 16 + quad * 4;
      const int b = row0 >> 11, t0 = row0 & (Tc - 1);
#pragma unroll
      for (int nt = 0; nt < 8; ++nt) {
        const int d = nt * 16 + col;
        alignas(8) bf16_t o[4];
#pragma unroll
        for (int i = 0; i < 4; ++i) o[i] = (bf16_t)acc[mt][nt][i];
        *(uint2*)(Vt + ((size_t)(b * KVc + kv) * HDc + d) * Tc + t0) = *(uint2*)o;
      }
    }
  }
}

// ---------------- Flash attention v14: T15 pipeline + waves_per_eu(2,2) --
// Rounds 10/11 proved launch_bounds' 2nd arg only sets a MINIMUM waves/EU:
// the allocator still targeted 4 waves/EU (128-reg budget) and spilled
// (~17MB scratch writes), identical binaries for (512,2) and (512,1).
// amdgpu_waves_per_eu(2,2) clamps the occupancy TARGET to 2 waves/EU ->
// 256-reg budget. LDS (130KB) already pins 1 block/CU = 2 waves/EU, so the
// clamp costs zero real occupancy; it only stops spill-for-occupancy.
__global__ __launch_bounds__(512)
__attribute__((amdgpu_waves_per_eu(2, 2))) void k_attn(
    const bf16_t* __restrict__ Qp, const bf16_t* __restrict__ Kp,
    const bf16_t* __restrict__ Vt, bf16_t* __restrict__ Oout) {
  constexpr float sc2 = 0.08838834764831845f * 1.4426950408889634f; // scale*log2(e)
  __shared__ alignas(16) bf16_t Ksh[2][2][64 * 128];  // [buf][parity], swz ^(r&7)
  __shared__ alignas(16) bf16_t Vsh[2][2][128 * 64];  // [buf][parity], swz ^(d&7)
  __shared__ float lex[4][64][2];                     // l exchange

  const int wg = blockIdx.x;
  const int g = wg & 7, kslot = wg >> 3;
  const int kvh = g & 3, b = g >> 2;
  const int h = kvh * 4 + (kslot >> 3);
  const int i2 = kslot & 7;

  const int tid = threadIdx.x, wave = tid >> 6, lane = tid & 63;
  const int wq = wave & 3, wk = wave >> 2;
  const int col = lane & 15, quad = lane >> 4;

  const bf16_t* Kb = Kp + (size_t)(b * KVc + kvh) * Tc * HDc;
  const bf16_t* Vb = Vt + (size_t)(b * KVc + kvh) * HDc * Tc;
  const bf16_t* Qbh = Qp + (size_t)(b * Hc + h) * Tc * HDc;

  const int st_kr = lane >> 4, st_kc8 = lane & 15;
  const int st_vr = lane >> 3, st_vc8 = lane & 7;

  const int qt0 = 15 - i2, qt1 = i2;
  const int PT0 = qt0 + 1;     // tiles in pass 0; 17 tiles total (s=0..16)

  const int q0p0 = qt0 * 128 + wq * 32;
  const int q0p1 = qt1 * 128 + wq * 32;
  int q0 = q0p0;

  // preload BOTH passes' Q fragments (removes boundary reload latency)
  bf16x8 qA0[4], qB0[4], qA1[4], qB1[4];
  {
    const bf16_t* a0 = Qbh + (size_t)(q0p0 + col) * HDc;
    const bf16_t* b0 = Qbh + (size_t)(q0p0 + 16 + col) * HDc;
    const bf16_t* a1 = Qbh + (size_t)(q0p1 + col) * HDc;
    const bf16_t* b1 = Qbh + (size_t)(q0p1 + 16 + col) * HDc;
#pragma unroll
    for (int kc = 0; kc < 4; ++kc) {
      bf16x8 r0 = *(const bf16x8*)(a0 + kc * 32 + quad * 8);
      bf16x8 r1 = *(const bf16x8*)(b0 + kc * 32 + quad * 8);
      bf16x8 r2 = *(const bf16x8*)(a1 + kc * 32 + quad * 8);
      bf16x8 r3 = *(const bf16x8*)(b1 + kc * 32 + quad * 8);
#pragma unroll
      for (int e = 0; e < 8; ++e) {
        qA0[kc][e] = (bf16_t)((float)r0[e] * sc2);
        qB0[kc][e] = (bf16_t)((float)r1[e] * sc2);
        qA1[kc][e] = (bf16_t)((float)r2[e] * sc2);
        qB1[kc][e] = (bf16_t)((float)r3[e] * sc2);
      }
    }
  }

  f32x4 oA[8], oB[8];
#pragma unroll
  for (int nb = 0; nb < 8; ++nb) {
    oA[nb] = f32x4{0.f, 0.f, 0.f, 0.f};
    oB[nb] = f32x4{0.f, 0.f, 0.f, 0.f};
  }
  float lA = 0.f, lB = 0.f;
  unsigned int pwA[4][2], pwB[4][2];   // saved P of tile r (consumed r+1)

  auto kvb_of = [&](int t) { const int tn = (t < PT0) ? t : t - PT0; return tn * 128 + wk * 64; };

  auto stageK = [&](int t) {
    bf16_t* Kd = &Ksh[t & 1][wk][0];
    const int kb = kvb_of(t);
#pragma unroll
    for (int i = 0; i < 4; ++i) {
      const int rb = wq * 16 + i * 4;
      const int r = rb + st_kr;
      const int kc8 = st_kc8 ^ (r & 7);
      gload_lds16(Kb + (size_t)(kb + r) * HDc + kc8 * 8, Kd + rb * 128);
    }
  };
  auto stageV = [&](int t) {
    bf16_t* Vd = &Vsh[t & 1][wk][0];
    const int kb = kvb_of(t);
#pragma unroll
    for (int i = 0; i < 4; ++i) {
      const int db = wq * 32 + i * 8;
      const int d = db + st_vr;
      const int tc8 = st_vc8 ^ (d & 7);
      gload_lds16(Vb + (size_t)d * Tc + kb + tc8 * 8, Vd + db * 64);
    }
  };

  auto qkc = [&](const bf16x8 (&qa)[4], const bf16x8 (&qb)[4],
                 f32x4 (&sA)[4], f32x4 (&sB)[4], const bf16_t* Kc) {
#pragma unroll
    for (int kc = 0; kc < 4; ++kc)
#pragma unroll
      for (int tb = 0; tb < 4; ++tb) {
        const int rr = tb * 16 + col;
        const int slot = (kc * 4 + quad) ^ (rr & 7);
        bf16x8 kf = *(const bf16x8*)(Kc + rr * 128 + slot * 8);
        sA[tb] = __builtin_amdgcn_mfma_f32_16x16x32_bf16(kf, qa[kc], sA[tb], 0, 0, 0);
        sB[tb] = __builtin_amdgcn_mfma_f32_16x16x32_bf16(kf, qb[kc], sB[tb], 0, 0, 0);
      }
  };

  auto pvc = [&](const bf16_t* Vc) {
#pragma unroll
    for (int kc = 0; kc < 2; ++kc) {
      unsigned int a0 = pwA[2 * kc][0], c0 = pwA[2 * kc + 1][0];
      unsigned int a1 = pwA[2 * kc][1], c1 = pwA[2 * kc + 1][1];
      perm32swap(a0, c0); perm32swap(a1, c1);
      perm16swap(a0, c0); perm16swap(a1, c1);
      union { unsigned int w[4]; bf16x8 v; } uA;
      uA.w[0] = a0; uA.w[1] = a1; uA.w[2] = c0; uA.w[3] = c1;
      unsigned int d0 = pwB[2 * kc][0], e0 = pwB[2 * kc + 1][0];
      unsigned int d1 = pwB[2 * kc][1], e1 = pwB[2 * kc + 1][1];
      perm32swap(d0, e0); perm32swap(d1, e1);
      perm16swap(d0, e0); perm16swap(d1, e1);
      union { unsigned int w[4]; bf16x8 v; } uB;
      uB.w[0] = d0; uB.w[1] = d1; uB.w[2] = e0; uB.w[3] = e1;
      const bf16x8 pfA = uA.v, pfB = uB.v;
#pragma unroll
      for (int nb = 0; nb < 8; ++nb) {
        const int d = nb * 16 + col;
        const int vslot = (kc * 4 + quad) ^ (d & 7);
        bf16x8 vf = *(const bf16x8*)(Vc + d * 64 + vslot * 8);
        oA[nb] = __builtin_amdgcn_mfma_f32_16x16x32_bf16(pfA, vf, oA[nb], 0, 0, 0);
        oB[nb] = __builtin_amdgcn_mfma_f32_16x16x32_bf16(pfB, vf, oB[nb], 0, 0, 0);
      }
    }
  };

  auto expp = [&](const f32x4 (&sA)[4], const f32x4 (&sB)[4], int kb, bool diag) {
    const int qrA = q0 + col, qrB = q0 + 16 + col;
#pragma unroll
    for (int tb = 0; tb < 4; ++tb) {
      const int kvb = kb + tb * 16 + quad * 4;
      float a0 = fast_exp2(sA[tb][0]), a1 = fast_exp2(sA[tb][1]);
      float a2 = fast_exp2(sA[tb][2]), a3 = fast_exp2(sA[tb][3]);
      float b0 = fast_exp2(sB[tb][0]), b1 = fast_exp2(sB[tb][1]);
      float b2 = fast_exp2(sB[tb][2]), b3 = fast_exp2(sB[tb][3]);
      if (diag) {
        a0 = (kvb + 0 > qrA) ? 0.f : a0;
        a1 = (kvb + 1 > qrA) ? 0.f : a1;
        a2 = (kvb + 2 > qrA) ? 0.f : a2;
        a3 = (kvb + 3 > qrA) ? 0.f : a3;
        b0 = (kvb + 0 > qrB) ? 0.f : b0;
        b1 = (kvb + 1 > qrB) ? 0.f : b1;
        b2 = (kvb + 2 > qrB) ? 0.f : b2;
        b3 = (kvb + 3 > qrB) ? 0.f : b3;
      }
      lA += (a0 + a1) + (a2 + a3);
      lB += (b0 + b1) + (b2 + b3);
      pwA[tb][0] = cvt_pk_bf16(a0, a1);
      pwA[tb][1] = cvt_pk_bf16(a2, a3);
      pwB[tb][0] = cvt_pk_bf16(b0, b1);
      pwB[tb][1] = cvt_pk_bf16(b2, b3);
    }
  };

  // two-half parity merge through a dead 32KB V buffer + O write
  auto combine = [&](float* dead, int q0o) {
    float* xo = dead + wq * 2048;
    asm volatile("s_barrier" ::: "memory");
    if (wk) {
#pragma unroll
      for (int nb = 0; nb < 8; ++nb) *(f32x4*)(xo + nb * 256 + lane * 4) = oA[nb];
      lex[wq][lane][0] = lA;
      lex[wq][lane][1] = lB;
    }
    asm volatile("s_waitcnt lgkmcnt(0)" ::: "memory");
    asm volatile("s_barrier" ::: "memory");
    if (!wk) {
#pragma unroll
      for (int nb = 0; nb < 8; ++nb) oA[nb] += *(const f32x4*)(xo + nb * 256 + lane * 4);
    }
    asm volatile("s_barrier" ::: "memory");
    if (wk) {
#pragma unroll
      for (int nb = 0; nb < 8; ++nb) *(f32x4*)(xo + nb * 256 + lane * 4) = oB[nb];
    }
    asm volatile("s_waitcnt lgkmcnt(0)" ::: "memory");
    asm volatile("s_barrier" ::: "memory");
    if (!wk) {
#pragma unroll
      for (int nb = 0; nb < 8; ++nb) oB[nb] += *(const f32x4*)(xo + nb * 256 + lane * 4);
      const float fA = lA + lex[wq][lane][0];
      const float fB = lB + lex[wq][lane][1];
#pragma unroll
      for (int gg = 0; gg < 2; ++gg) {
        float rs = gg ? fB : fA;
        rs += __shfl_xor(rs, 16);
        rs += __shfl_xor(rs, 32);
        const float inv = 1.0f / rs;
        const f32x4* oa = gg ? oB : oA;
        const int qbase = q0o + gg * 16;
#pragma unroll
        for (int i = 0; i < 4; ++i) {
          const float iq = __shfl(inv, quad * 4 + i);
          const int qrow = qbase + quad * 4 + i;
          bf16_t* op = Oout + ((size_t)(b * Tc) + qrow) * (Hc * HDc) + h * HDc;
#pragma unroll
          for (int nb = 0; nb < 8; ++nb) op[nb * 16 + col] = (bf16_t)(oa[nb][i] * iq);
        }
      }
    }
  };

  // prologue: K(0) + V(0) in flight (8 loads -> uniform vmcnt(8) at r=0)
  stageK(0); stageV(0);

#pragma unroll 1
  for (int r = 0; r <= 16; ++r) {
    asm volatile("s_barrier" ::: "memory");
    stageK(r < 16 ? r + 1 : 16);   // K one region ahead (dup at r=16 benign)
    stageV(r);                     // V consumed next region (dup at r=0 benign)
    asm volatile("s_waitcnt vmcnt(8)" ::: "memory");
    asm volatile("s_barrier" ::: "memory");

    f32x4 stA[4], stB[4];
#pragma unroll
    for (int tb = 0; tb < 4; ++tb) {
      stA[tb] = f32x4{0.f, 0.f, 0.f, 0.f};
      stB[tb] = f32x4{0.f, 0.f, 0.f, 0.f};
    }
    const bf16_t* Kc = &Ksh[r & 1][wk][0];
    __builtin_amdgcn_s_setprio(1);
    if (r < PT0) qkc(qA0, qB0, stA, stB, Kc);
    else         qkc(qA1, qB1, stA, stB, Kc);
    if (r >= 1)  pvc(&Vsh[(r - 1) & 1][wk][0]);   // deferred PV of tile r-1
    __builtin_amdgcn_s_setprio(0);

    if (r == PT0) {   // pass-0 accumulators complete (PV(PT0-1) just done)
      combine((float*)&Vsh[(PT0 - 1) & 1][0][0], q0);
#pragma unroll
      for (int nb = 0; nb < 8; ++nb) {
        oA[nb] = f32x4{0.f, 0.f, 0.f, 0.f};
        oB[nb] = f32x4{0.f, 0.f, 0.f, 0.f};
      }
      lA = 0.f; lB = 0.f;
      q0 = q0p1;
    }

    const bool diag = (r == PT0 - 1) || (r == 16);
    expp(stA, stB, kvb_of(r), diag);   // P for tile r -> consumed region r+1
  }

  // epilogue region: PV(16) + pass-1 merge
  asm volatile("s_barrier" ::: "memory");
  asm volatile("s_waitcnt vmcnt(0)" ::: "memory");
  asm volatile("s_barrier" ::: "memory");
  __builtin_amdgcn_s_setprio(1);
  pvc(&Vsh[0][wk][0]);                 // V(16) is in buffer 0
  __builtin_amdgcn_s_setprio(0);
  combine((float*)&Vsh[1][0][0], q0);  // buffer 1 (V(15)) is dead
}

// ---------------- launch ----------------
extern "C" void kernel_launch(void* const* d_in, const int* in_sizes, int n_in,
                              void* d_out, int out_size, void* d_ws, size_t ws_size,
                              hipStream_t stream) {
  (void)in_sizes; (void)n_in; (void)out_size; (void)ws_size;
  const float* x    = (const float*)d_in[0];
  const float* cosT = (const float*)d_in[1];
  const float* sinT = (const float*)d_in[2];
  const float* Wq   = (const float*)d_in[3];
  const float* Wk   = (const float*)d_in[4];
  const float* Wv   = (const float*)d_in[5];
  const float* Wo   = (const float*)d_in[6];
  float* out = (float*)d_out;

  char* ws = (char*)d_ws;
  size_t off = 0;
  auto take = [&](size_t bytes) { char* p = ws + off; off += (bytes + 255) & ~(size_t)255; return p; };

  bf16_t* xb    = (bf16_t*)take((size_t)Mc * Cdim * 2);      // reused as attn-out
  bf16_t* Wqkvt = (bf16_t*)take((size_t)Nqkv * Cdim * 2);    // [3072][2048]
  bf16_t* Wot   = (bf16_t*)take((size_t)Cdim * (Hc * HDc) * 2);
  bf16_t* Qp    = (bf16_t*)take((size_t)Mc * (Hc * HDc) * 2);
  bf16_t* Kp    = (bf16_t*)take((size_t)Mc * (KVc * HDc) * 2);
  bf16_t* Vt    = (bf16_t*)take((size_t)Mc * (KVc * HDc) * 2);
  bf16_t* Wqt = Wqkvt;
  bf16_t* Wkt = Wqkvt + (size_t)2048 * Cdim;
  bf16_t* Wvt = Wqkvt + (size_t)2560 * Cdim;
  bf16_t* attn = xb;   // xb dead after QKV projection

  // 1. prep: convert x + transpose-convert all weights (one launch)
  k_prep<<<dim3(4096 + 1024 + 256 + 256 + 1024), dim3(256), 0, stream>>>(
      x, xb, Wq, Wk, Wv, Wo, Wqt, Wkt, Wvt, Wot);
  // 2. fused QKV projection + RoPE + repack + V-transpose (768 blocks, 3/CU)
  k_gemm_qkv<<<dim3(Nqkv / 128, Mc / 128), dim3(256), 0, stream>>>(
      xb, Wqkvt, cosT, sinT, Qp, Kp, Vt);
  // 3. attention: 256 blocks x 512 threads, kvh-grouped XCD mapping
  k_attn<<<dim3(256), dim3(512), 0, stream>>>(Qp, Kp, Vt, attn);
  // 4. output projection, fp32 out
  k_gemm_bt<<<dim3(Cdim / 128, Mc / 128), dim3(256), 0, stream>>>(
      attn, Wot, out, Mc, Cdim, Hc * HDc);
}

// Round 13
// 264.564 us; speedup vs baseline: 1.0958x; 1.0470x over previous
//
#include <hip/hip_runtime.h>
#include <hip/hip_bf16.h>
#include <math.h>

typedef __bf16 bf16_t;
typedef __bf16 bf16x8 __attribute__((ext_vector_type(8)));
typedef float f32x4 __attribute__((ext_vector_type(4)));

constexpr int Bc = 2, Tc = 2048, Cdim = 2048, Hc = 16, KVc = 4, HDc = 128;
constexpr int Mc = Bc * Tc;      // 4096
constexpr int Nqkv = 3072;       // fused projection width: 2048 Q + 512 K + 512 V

typedef const __attribute__((address_space(1))) void* as1_cptr;
typedef __attribute__((address_space(3))) void* as3_ptr;

__device__ __forceinline__ void gload_lds16(const bf16_t* g, bf16_t* l) {
  __builtin_amdgcn_global_load_lds((as1_cptr)(const void*)g, (as3_ptr)(void*)l, 16, 0, 0);
}

__device__ __forceinline__ unsigned int cvt_pk_bf16(float lo, float hi) {
  unsigned int r;
  asm("v_cvt_pk_bf16_f32 %0, %1, %2" : "=v"(r) : "v"(lo), "v"(hi));
  return r;
}
__device__ __forceinline__ void perm32swap(unsigned int& a, unsigned int& b) {
  asm("v_permlane32_swap_b32 %0, %1" : "+v"(a), "+v"(b));
}
__device__ __forceinline__ void perm16swap(unsigned int& a, unsigned int& b) {
  asm("v_permlane16_swap_b32 %0, %1" : "+v"(a), "+v"(b));
}
// guaranteed single-instruction exp2 (inputs bounded, no denormal concerns)
__device__ __forceinline__ float fast_exp2(float x) {
  float r;
  asm("v_exp_f32 %0, %1" : "=v"(r) : "v"(x));
  return r;
}

// ---------------- prep: x f32->bf16 + 4 weight transpose-converts, 1 launch
// tile padded [64][73]: at [64][72] the transpose-read hit a ~16-way bank
// conflict (row dword-stride 36 -> bank step 16 mod 32 across kc-groups);
// 73 gives step 18 (odd half-stride) -> all 16 group banks distinct.
__global__ void k_prep(const float* __restrict__ x, bf16_t* __restrict__ xb,
                       const float* __restrict__ Wq, const float* __restrict__ Wk,
                       const float* __restrict__ Wv, const float* __restrict__ Wo,
                       bf16_t* __restrict__ Wqt, bf16_t* __restrict__ Wkt,
                       bf16_t* __restrict__ Wvt, bf16_t* __restrict__ Wot) {
  __shared__ bf16_t tile[64][73];
  int bid = blockIdx.x;
  if (bid < 4096) {
    int i = (bid * 256 + threadIdx.x) * 8;
    float4 a = *(const float4*)(x + i);
    float4 b = *(const float4*)(x + i + 4);
    bf16x8 v;
    v[0] = (bf16_t)a.x; v[1] = (bf16_t)a.y; v[2] = (bf16_t)a.z; v[3] = (bf16_t)a.w;
    v[4] = (bf16_t)b.x; v[5] = (bf16_t)b.y; v[6] = (bf16_t)b.z; v[7] = (bf16_t)b.w;
    *(bf16x8*)(xb + i) = v;
    return;
  }
  bid -= 4096;
  const float* W; bf16_t* Wt; int K, N, k0, n0;
  if (bid < 1024)      { W = Wq; Wt = Wqt; K = 2048; N = 2048; k0 = (bid >> 5) * 64; n0 = (bid & 31) * 64; }
  else if (bid < 1280) { bid -= 1024; W = Wk; Wt = Wkt; K = 2048; N = 512; k0 = (bid >> 3) * 64; n0 = (bid & 7) * 64; }
  else if (bid < 1536) { bid -= 1280; W = Wv; Wt = Wvt; K = 2048; N = 512; k0 = (bid >> 3) * 64; n0 = (bid & 7) * 64; }
  else                 { bid -= 1536; W = Wo; Wt = Wot; K = 2048; N = 2048; k0 = (bid >> 5) * 64; n0 = (bid & 31) * 64; }
  const int t = threadIdx.x;
#pragma unroll
  for (int i = 0; i < 4; ++i) {
    int idx = t + i * 256;
    int r = idx >> 4;
    int c4 = (idx & 15) * 4;
    float4 v = *(const float4*)(W + (size_t)(k0 + r) * N + n0 + c4);
    tile[r][c4 + 0] = (bf16_t)v.x; tile[r][c4 + 1] = (bf16_t)v.y;
    tile[r][c4 + 2] = (bf16_t)v.z; tile[r][c4 + 3] = (bf16_t)v.w;
  }
  __syncthreads();
#pragma unroll
  for (int i = 0; i < 4; ++i) {
    int idx = t + i * 256;
    int n = idx >> 4;
    int kc = (idx & 15) * 4;
    alignas(8) bf16_t o[4];
#pragma unroll
    for (int j = 0; j < 4; ++j) o[j] = tile[kc + j][n];
    *(uint2*)(Wt + (size_t)(n0 + n) * K + k0 + kc) = *(uint2*)o;
  }
}

// ---------------- GEMM: C[M,N] = A[M,K] * Bt[N,K]^T (fp32 out, O-proj) ----
// 16x16x32 MFMA (32x32x16 operand pattern measured +4cyc/b128 bank conflict
// -> reverted). 512 blocks = exactly 2/CU, no dispatch tail.
__global__ __launch_bounds__(256, 2) void k_gemm_bt(
    const bf16_t* __restrict__ A, const bf16_t* __restrict__ Bt,
    float* __restrict__ Cout, int M, int N, int K) {
  __shared__ alignas(16) bf16_t Ash[128 * 64];
  __shared__ alignas(16) bf16_t Bsh[128 * 64];
  const int tid = threadIdx.x;
  const int wave = tid >> 6, lane = tid & 63;
  const int col = lane & 15, quad = lane >> 4;
  // XCD-bijective swizzle: same-XCD blocks process consecutive tiles
  const int gx = gridDim.x;
  const int nwg = gx * gridDim.y;
  int wg = blockIdx.y * gx + blockIdx.x;
  if ((nwg & 7) == 0) wg = (wg & 7) * (nwg >> 3) + (wg >> 3);
  const int m0 = (wg / gx) * 128, n0 = (wg % gx) * 128;
  const int wr = wave >> 1, wc = wave & 1;

  f32x4 acc[4][4];
#pragma unroll
  for (int i = 0; i < 4; ++i)
#pragma unroll
    for (int j = 0; j < 4; ++j) acc[i][j] = f32x4{0.f, 0.f, 0.f, 0.f};

  const int lrow = lane >> 3;
  const int lkc8 = (lane & 7) ^ lrow;

  for (int k0 = 0; k0 < K; k0 += 64) {
    __syncthreads();
#pragma unroll
    for (int i = 0; i < 4; ++i) {
      const int rb = wave * 32 + i * 8;
      gload_lds16(A + (size_t)(m0 + rb + lrow) * K + k0 + lkc8 * 8, Ash + rb * 64);
      gload_lds16(Bt + (size_t)(n0 + rb + lrow) * K + k0 + lkc8 * 8, Bsh + rb * 64);
    }
    __syncthreads();
#pragma unroll
    for (int kc = 0; kc < 2; ++kc) {
      bf16x8 af[4], bfr[4];
#pragma unroll
      for (int mt = 0; mt < 4; ++mt) {
        const int m = wr * 64 + mt * 16 + col;
        const int slot = (kc * 4 + quad) ^ (m & 7);
        af[mt] = *(const bf16x8*)(Ash + m * 64 + slot * 8);
      }
#pragma unroll
      for (int nt = 0; nt < 4; ++nt) {
        const int n = wc * 64 + nt * 16 + col;
        const int slot = (kc * 4 + quad) ^ (n & 7);
        bfr[nt] = *(const bf16x8*)(Bsh + n * 64 + slot * 8);
      }
#pragma unroll
      for (int mt = 0; mt < 4; ++mt)
#pragma unroll
        for (int nt = 0; nt < 4; ++nt)
          acc[mt][nt] = __builtin_amdgcn_mfma_f32_16x16x32_bf16(
              af[mt], bfr[nt], acc[mt][nt], 0, 0, 0);
    }
  }
#pragma unroll
  for (int mt = 0; mt < 4; ++mt)
#pragma unroll
    for (int i = 0; i < 4; ++i) {
      const int row = m0 + wr * 64 + mt * 16 + quad * 4 + i;
#pragma unroll
      for (int nt = 0; nt < 4; ++nt)
        Cout[(size_t)row * N + n0 + wc * 64 + nt * 16 + col] = acc[mt][nt][i];
    }
}

// ---------------- fused QKV GEMM + RoPE + head-repack + V-transpose ------
// 16x16x32. 768 blocks at (256,3): all co-resident, no tail.
__global__ __launch_bounds__(256, 3) void k_gemm_qkv(
    const bf16_t* __restrict__ A, const bf16_t* __restrict__ Bt,
    const float* __restrict__ cs, const float* __restrict__ sn,
    bf16_t* __restrict__ Qp, bf16_t* __restrict__ Kp, bf16_t* __restrict__ Vt) {
  constexpr int K = Cdim;
  __shared__ alignas(16) bf16_t Ash[128 * 64];
  __shared__ alignas(16) bf16_t Bsh[128 * 64];
  const int tid = threadIdx.x;
  const int wave = tid >> 6, lane = tid & 63;
  const int col = lane & 15, quad = lane >> 4;
  // XCD-bijective swizzle (nwg = 768, %8 == 0)
  const int gx = gridDim.x;
  const int nwg = gx * gridDim.y;
  int wg = blockIdx.y * gx + blockIdx.x;
  wg = (wg & 7) * (nwg >> 3) + (wg >> 3);
  const int m0 = (wg / gx) * 128;
  const int bxi = wg % gx;
  const int n0 = bxi * 128;

  f32x4 acc[2][8];
#pragma unroll
  for (int i = 0; i < 2; ++i)
#pragma unroll
    for (int j = 0; j < 8; ++j) acc[i][j] = f32x4{0.f, 0.f, 0.f, 0.f};

  const int lrow = lane >> 3;
  const int lkc8 = (lane & 7) ^ lrow;

  for (int k0 = 0; k0 < K; k0 += 64) {
    __syncthreads();
#pragma unroll
    for (int i = 0; i < 4; ++i) {
      const int rb = wave * 32 + i * 8;
      gload_lds16(A + (size_t)(m0 + rb + lrow) * K + k0 + lkc8 * 8, Ash + rb * 64);
      gload_lds16(Bt + (size_t)(n0 + rb + lrow) * K + k0 + lkc8 * 8, Bsh + rb * 64);
    }
    __syncthreads();
#pragma unroll
    for (int kc = 0; kc < 2; ++kc) {
      bf16x8 af[2], bfr[8];
#pragma unroll
      for (int mt = 0; mt < 2; ++mt) {
        const int m = wave * 32 + mt * 16 + col;
        const int slot = (kc * 4 + quad) ^ (m & 7);
        af[mt] = *(const bf16x8*)(Ash + m * 64 + slot * 8);
      }
#pragma unroll
      for (int nt = 0; nt < 8; ++nt) {
        const int n = nt * 16 + col;
        const int slot = (kc * 4 + quad) ^ (n & 7);
        bfr[nt] = *(const bf16x8*)(Bsh + n * 64 + slot * 8);
      }
#pragma unroll
      for (int mt = 0; mt < 2; ++mt)
#pragma unroll
        for (int nt = 0; nt < 8; ++nt)
          acc[mt][nt] = __builtin_amdgcn_mfma_f32_16x16x32_bf16(
              af[mt], bfr[nt], acc[mt][nt], 0, 0, 0);
    }
  }

  const int bx = bxi;   // head-tile: 0-15 Q, 16-19 K, 20-23 V
  if (bx < 20) {
    const bool isQ = bx < 16;
#pragma unroll
    for (int mt = 0; mt < 2; ++mt)
#pragma unroll
      for (int i = 0; i < 4; ++i) {
        const int row = m0 + wave * 32 + mt * 16 + quad * 4 + i;
        const int b = row >> 11, t = row & (Tc - 1);
        bf16_t* op = isQ ? Qp + ((size_t)(b * Hc + bx) * Tc + t) * HDc
                         : Kp + ((size_t)(b * KVc + (bx - 16)) * Tc + t) * HDc;
        const float* cr = cs + t * HDc;
        const float* sr = sn + t * HDc;
#pragma unroll
        for (int nt = 0; nt < 4; ++nt) {
          const int d = nt * 16 + col;
          const float c = cr[d], s = sr[d];
          const float x0 = acc[mt][nt][i], x1 = acc[mt][nt + 4][i];
          op[d]      = (bf16_t)(x0 * c - x1 * s);
          op[d + 64] = (bf16_t)(x1 * c + x0 * s);
        }
      }
  } else {
    const int kv = bx - 20;
#pragma unroll
    for (int mt = 0; mt < 2; ++mt) {
      const int row0 = m0 + wave * 32 + mt * 16 + quad * 4;
      const int b = row0 >> 11, t0 = row0 & (Tc - 1);
#pragma unroll
      for (int nt = 0; nt < 8; ++nt) {
        const int d = nt * 16 + col;
        alignas(8) bf16_t o[4];
#pragma unroll
        for (int i = 0; i < 4; ++i) o[i] = (bf16_t)acc[mt][nt][i];
        *(uint2*)(Vt + ((size_t)(b * KVc + kv) * HDc + d) * Tc + t0) = *(uint2*)o;
      }
    }
  }
}

// ---------------- Flash attention v11 (reverted: best measured, 65.8us) --
// T15 cross-iteration pipeline (rounds 10-12) closed: its ~160-reg live set
// spills at the allocator's immovable 128-reg budget for 512-thread blocks
// (launch_bounds min-arg and amdgpu_waves_per_eu both ineffective), and the
// spill tax (17MB scratch) exceeds the VALU-hiding win. v11 fits at 104.
__global__ __launch_bounds__(512, 2) void k_attn(
    const bf16_t* __restrict__ Qp, const bf16_t* __restrict__ Kp,
    const bf16_t* __restrict__ Vt, bf16_t* __restrict__ Oout) {
  constexpr float sc2 = 0.08838834764831845f * 1.4426950408889634f; // scale*log2(e)
  __shared__ alignas(16) bf16_t Ksh[2][2][64 * 128];  // [buf][parity], swz ^(r&7)
  __shared__ alignas(16) bf16_t Vsh[2][2][128 * 64];  // [buf][parity], swz ^(d&7)
  __shared__ float lex[4][64][2];                     // l exchange

  // decode: g = XCD group (kv-set), k = slot within group
  const int wg = blockIdx.x;
  const int g = wg & 7, k = wg >> 3;
  const int kvh = g & 3, b = g >> 2;
  const int h = kvh * 4 + (k >> 3);
  const int i2 = k & 7;

  const int tid = threadIdx.x, wave = tid >> 6, lane = tid & 63;
  const int wq = wave & 3, wk = wave >> 2;
  const int col = lane & 15, quad = lane >> 4;

  const bf16_t* Kb = Kp + (size_t)(b * KVc + kvh) * Tc * HDc;
  const bf16_t* Vb = Vt + (size_t)(b * KVc + kvh) * HDc * Tc;
  const bf16_t* Qbh = Qp + (size_t)(b * Hc + h) * Tc * HDc;

  const int st_kr = lane >> 4, st_kc8 = lane & 15;
  const int st_vr = lane >> 3, st_vc8 = lane & 7;

  const int qt0 = 15 - i2, qt1 = i2;     // 128-row q-tiles
  const int PT0 = qt0 + 1;               // pair-iters in pass 0
  const int PTOT = 17;                   // PT0 + PT1 for every i2

  int q0 = qt0 * 128 + wq * 32;          // wave's 32-q base

  bf16x8 qfA[4], qfB[4];
  {
    const bf16_t* qa = Qbh + (size_t)(q0 + col) * HDc;
    const bf16_t* qb = Qbh + (size_t)(q0 + 16 + col) * HDc;
#pragma unroll
    for (int kc = 0; kc < 4; ++kc) {
      bf16x8 ra = *(const bf16x8*)(qa + kc * 32 + quad * 8);
      bf16x8 rb = *(const bf16x8*)(qb + kc * 32 + quad * 8);
#pragma unroll
      for (int e = 0; e < 8; ++e) {
        qfA[kc][e] = (bf16_t)((float)ra[e] * sc2);
        qfB[kc][e] = (bf16_t)((float)rb[e] * sc2);
      }
    }
  }

  f32x4 o_accA[8], o_accB[8];
#pragma unroll
  for (int nb = 0; nb < 8; ++nb) {
    o_accA[nb] = f32x4{0.f, 0.f, 0.f, 0.f};
    o_accB[nb] = f32x4{0.f, 0.f, 0.f, 0.f};
  }
  float l_iA = 0.f, l_iB = 0.f;

  // stage this wave's parity tile of a kv pair (8 gloads)
  auto stage = [&](int bufi, int kbase) {
    bf16_t* Kd = &Ksh[bufi][wk][0];
    bf16_t* Vd = &Vsh[bufi][wk][0];
    const int kb = kbase + wk * 64;
#pragma unroll
    for (int i = 0; i < 4; ++i) {
      const int rb = wq * 16 + i * 4;
      const int r = rb + st_kr;
      const int kc8 = st_kc8 ^ (r & 7);
      gload_lds16(Kb + (size_t)(kb + r) * HDc + kc8 * 8, Kd + rb * 128);
      const int db = wq * 32 + i * 8;
      const int d = db + st_vr;
      const int tc8 = st_vc8 ^ (d & 7);
      gload_lds16(Vb + (size_t)d * Tc + kb + tc8 * 8, Vd + db * 64);
    }
  };

  // parity merge through dead buffer bufc + even-wave O write
  auto combine = [&](int bufc) {
    asm volatile("s_barrier" ::: "memory");
    float* xo = (wq < 2) ? (float*)(&Ksh[bufc][0][0]) + wq * 4096
                         : (float*)(&Vsh[bufc][0][0]) + (wq - 2) * 4096;
    if (wk) {
#pragma unroll
      for (int nb = 0; nb < 8; ++nb) {
        *(f32x4*)(xo + nb * 256 + lane * 4) = o_accA[nb];
        *(f32x4*)(xo + (8 + nb) * 256 + lane * 4) = o_accB[nb];
      }
      lex[wq][lane][0] = l_iA;
      lex[wq][lane][1] = l_iB;
    }
    asm volatile("s_waitcnt lgkmcnt(0)" ::: "memory");
    asm volatile("s_barrier" ::: "memory");
    if (!wk) {
#pragma unroll
      for (int nb = 0; nb < 8; ++nb) {
        o_accA[nb] += *(const f32x4*)(xo + nb * 256 + lane * 4);
        o_accB[nb] += *(const f32x4*)(xo + (8 + nb) * 256 + lane * 4);
      }
      float lA = l_iA + lex[wq][lane][0];
      float lB = l_iB + lex[wq][lane][1];
#pragma unroll
      for (int gg = 0; gg < 2; ++gg) {
        float rs = gg ? lB : lA;
        rs += __shfl_xor(rs, 16);
        rs += __shfl_xor(rs, 32);
        const float inv = 1.0f / rs;
        const f32x4* oa = gg ? o_accB : o_accA;
        const int qbase = q0 + gg * 16;
#pragma unroll
        for (int i = 0; i < 4; ++i) {
          const float iq = __shfl(inv, quad * 4 + i);
          const int qrow = qbase + quad * 4 + i;
          bf16_t* op = Oout + ((size_t)(b * Tc) + qrow) * (Hc * HDc) + h * HDc;
#pragma unroll
          for (int nb = 0; nb < 8; ++nb) op[nb * 16 + col] = (bf16_t)(oa[nb][i] * iq);
        }
      }
    }
  };

  // prologue: stage pair 0 into buffer 0
  stage(0, 0);

#pragma unroll 1
  for (int t = 0; t < PTOT; ++t) {
    const int cur = t & 1;
    const bool diag = (t == PT0 - 1) || (t == PTOT - 1);
    const int tn = (t < PT0) ? t : t - PT0;
    const int kb = tn * 128 + wk * 64;     // this wave's kv-tile base
    asm volatile("s_barrier" ::: "memory");
    {
      const int jn = (t + 1 < PTOT) ? (t + 1) : (PTOT - 1);
      const int tnn = (jn < PT0) ? jn : jn - PT0;
      stage(cur ^ 1, tnn * 128);
    }
    asm volatile("s_waitcnt vmcnt(8)" ::: "memory");
    asm volatile("s_barrier" ::: "memory");

    const bf16_t* Kc = &Ksh[cur][wk][0];
    const bf16_t* Vc = &Vsh[cur][wk][0];

    // S^T tiles for both q-groups: each kf read feeds 2 MFMAs
    f32x4 stA[4], stB[4];
#pragma unroll
    for (int tb = 0; tb < 4; ++tb) {
      stA[tb] = f32x4{0.f, 0.f, 0.f, 0.f};
      stB[tb] = f32x4{0.f, 0.f, 0.f, 0.f};
    }
    __builtin_amdgcn_s_setprio(1);
#pragma unroll
    for (int kc = 0; kc < 4; ++kc)
#pragma unroll
      for (int tb = 0; tb < 4; ++tb) {
        const int r = tb * 16 + col;
        const int slot = (kc * 4 + quad) ^ (r & 7);
        bf16x8 kf = *(const bf16x8*)(Kc + r * 128 + slot * 8);
        stA[tb] = __builtin_amdgcn_mfma_f32_16x16x32_bf16(kf, qfA[kc], stA[tb], 0, 0, 0);
        stB[tb] = __builtin_amdgcn_mfma_f32_16x16x32_bf16(kf, qfB[kc], stB[tb], 0, 0, 0);
      }
    __builtin_amdgcn_s_setprio(0);

    // p = exp2(s); causal mask via global kv-vs-q compare on diag pair
    unsigned int pwA[4][2], pwB[4][2];
    const int qrA = q0 + col, qrB = q0 + 16 + col;
#pragma unroll
    for (int tb = 0; tb < 4; ++tb) {
      const int kvb = kb + tb * 16 + quad * 4;
      float a0 = fast_exp2(stA[tb][0]), a1 = fast_exp2(stA[tb][1]);
      float a2 = fast_exp2(stA[tb][2]), a3 = fast_exp2(stA[tb][3]);
      float b0 = fast_exp2(stB[tb][0]), b1 = fast_exp2(stB[tb][1]);
      float b2 = fast_exp2(stB[tb][2]), b3 = fast_exp2(stB[tb][3]);
      if (diag) {
        a0 = (kvb + 0 > qrA) ? 0.f : a0;
        a1 = (kvb + 1 > qrA) ? 0.f : a1;
        a2 = (kvb + 2 > qrA) ? 0.f : a2;
        a3 = (kvb + 3 > qrA) ? 0.f : a3;
        b0 = (kvb + 0 > qrB) ? 0.f : b0;
        b1 = (kvb + 1 > qrB) ? 0.f : b1;
        b2 = (kvb + 2 > qrB) ? 0.f : b2;
        b3 = (kvb + 3 > qrB) ? 0.f : b3;
      }
      l_iA += (a0 + a1) + (a2 + a3);
      l_iB += (b0 + b1) + (b2 + b3);
      pwA[tb][0] = cvt_pk_bf16(a0, a1);
      pwA[tb][1] = cvt_pk_bf16(a2, a3);
      pwB[tb][0] = cvt_pk_bf16(b0, b1);
      pwB[tb][1] = cvt_pk_bf16(b2, b3);
    }

    // O += P V : each vf read feeds 2 MFMAs
#pragma unroll
    for (int kc = 0; kc < 2; ++kc) {
      unsigned int a0 = pwA[2 * kc][0], c0 = pwA[2 * kc + 1][0];
      unsigned int a1 = pwA[2 * kc][1], c1 = pwA[2 * kc + 1][1];
      perm32swap(a0, c0); perm32swap(a1, c1);
      perm16swap(a0, c0); perm16swap(a1, c1);
      union { unsigned int w[4]; bf16x8 v; } uA;
      uA.w[0] = a0; uA.w[1] = a1; uA.w[2] = c0; uA.w[3] = c1;
      unsigned int d0 = pwB[2 * kc][0], e0 = pwB[2 * kc + 1][0];
      unsigned int d1 = pwB[2 * kc][1], e1 = pwB[2 * kc + 1][1];
      perm32swap(d0, e0); perm32swap(d1, e1);
      perm16swap(d0, e0); perm16swap(d1, e1);
      union { unsigned int w[4]; bf16x8 v; } uB;
      uB.w[0] = d0; uB.w[1] = d1; uB.w[2] = e0; uB.w[3] = e1;
      const bf16x8 pfA = uA.v, pfB = uB.v;
      __builtin_amdgcn_s_setprio(1);
#pragma unroll
      for (int nb = 0; nb < 8; ++nb) {
        const int d = nb * 16 + col;
        const int vslot = (kc * 4 + quad) ^ (d & 7);
        bf16x8 vf = *(const bf16x8*)(Vc + d * 64 + vslot * 8);
        o_accA[nb] = __builtin_amdgcn_mfma_f32_16x16x32_bf16(pfA, vf, o_accA[nb], 0, 0, 0);
        o_accB[nb] = __builtin_amdgcn_mfma_f32_16x16x32_bf16(pfB, vf, o_accB[nb], 0, 0, 0);
      }
      __builtin_amdgcn_s_setprio(0);
    }

    // pass-0 boundary: merge parities, write O, reset, reload pass-1 Q
    if (t == PT0 - 1) {
      combine(cur);
      l_iA = 0.f; l_iB = 0.f;
#pragma unroll
      for (int nb = 0; nb < 8; ++nb) {
        o_accA[nb] = f32x4{0.f, 0.f, 0.f, 0.f};
        o_accB[nb] = f32x4{0.f, 0.f, 0.f, 0.f};
      }
      q0 = qt1 * 128 + wq * 32;
      const bf16_t* qa = Qbh + (size_t)(q0 + col) * HDc;
      const bf16_t* qb = Qbh + (size_t)(q0 + 16 + col) * HDc;
#pragma unroll
      for (int kc = 0; kc < 4; ++kc) {
        bf16x8 ra = *(const bf16x8*)(qa + kc * 32 + quad * 8);
        bf16x8 rb = *(const bf16x8*)(qb + kc * 32 + quad * 8);
#pragma unroll
        for (int e = 0; e < 8; ++e) {
          qfA[kc][e] = (bf16_t)((float)ra[e] * sc2);
          qfB[kc][e] = (bf16_t)((float)rb[e] * sc2);
        }
      }
    }
  }

  // pass-1 epilogue
  combine((PTOT - 1) & 1);
}

// ---------------- launch ----------------
extern "C" void kernel_launch(void* const* d_in, const int* in_sizes, int n_in,
                              void* d_out, int out_size, void* d_ws, size_t ws_size,
                              hipStream_t stream) {
  (void)in_sizes; (void)n_in; (void)out_size; (void)ws_size;
  const float* x    = (const float*)d_in[0];
  const float* cosT = (const float*)d_in[1];
  const float* sinT = (const float*)d_in[2];
  const float* Wq   = (const float*)d_in[3];
  const float* Wk   = (const float*)d_in[4];
  const float* Wv   = (const float*)d_in[5];
  const float* Wo   = (const float*)d_in[6];
  float* out = (float*)d_out;

  char* ws = (char*)d_ws;
  size_t off = 0;
  auto take = [&](size_t bytes) { char* p = ws + off; off += (bytes + 255) & ~(size_t)255; return p; };

  bf16_t* xb    = (bf16_t*)take((size_t)Mc * Cdim * 2);      // reused as attn-out
  bf16_t* Wqkvt = (bf16_t*)take((size_t)Nqkv * Cdim * 2);    // [3072][2048]
  bf16_t* Wot   = (bf16_t*)take((size_t)Cdim * (Hc * HDc) * 2);
  bf16_t* Qp    = (bf16_t*)take((size_t)Mc * (Hc * HDc) * 2);
  bf16_t* Kp    = (bf16_t*)take((size_t)Mc * (KVc * HDc) * 2);
  bf16_t* Vt    = (bf16_t*)take((size_t)Mc * (KVc * HDc) * 2);
  bf16_t* Wqt = Wqkvt;
  bf16_t* Wkt = Wqkvt + (size_t)2048 * Cdim;
  bf16_t* Wvt = Wqkvt + (size_t)2560 * Cdim;
  bf16_t* attn = xb;   // xb dead after QKV projection

  // 1. prep: convert x + transpose-convert all weights (one launch)
  k_prep<<<dim3(4096 + 1024 + 256 + 256 + 1024), dim3(256), 0, stream>>>(
      x, xb, Wq, Wk, Wv, Wo, Wqt, Wkt, Wvt, Wot);
  // 2. fused QKV projection + RoPE + repack + V-transpose (768 blocks, 3/CU)
  k_gemm_qkv<<<dim3(Nqkv / 128, Mc / 128), dim3(256), 0, stream>>>(
      xb, Wqkvt, cosT, sinT, Qp, Kp, Vt);
  // 3. attention: 256 blocks x 512 threads, kvh-grouped XCD mapping
  k_attn<<<dim3(256), dim3(512), 0, stream>>>(Qp, Kp, Vt, attn);
  // 4. output projection, fp32 out
  k_gemm_bt<<<dim3(Cdim / 128, Mc / 128), dim3(256), 0, stream>>>(
      attn, Wot, out, Mc, Cdim, Hc * HDc);
}